// Round 10
// baseline (952.760 us; speedup 1.0000x reference)
//
#include <hip/hip_runtime.h>
#include <stdint.h>

typedef __attribute__((ext_vector_type(8))) __bf16 bf16x8;
typedef __attribute__((ext_vector_type(8))) short short8;
typedef __attribute__((ext_vector_type(4))) float f32x4;

#define LOG_P01 (-2.302585093f)   // log(0.1)

__device__ __forceinline__ uint16_t f2bf(float f) {
  union { float f; uint32_t u; } v; v.f = f;
  uint32_t r = (v.u + 0x7fffu + ((v.u >> 16) & 1u)) >> 16;
  return (uint16_t)r;
}
__device__ __forceinline__ float bf2f(uint16_t u) {
  union { uint32_t u; float f; } v; v.u = ((uint32_t)u) << 16;
  return v.f;
}
__device__ __forceinline__ float softplus1(float x) { return 1e-6f + log1pf(expf(x)); }

__device__ __forceinline__ void gload16(const void* g, void* l) {
  __builtin_amdgcn_global_load_lds(
      (__attribute__((address_space(1))) void*)(g),
      (__attribute__((address_space(3))) void*)(l), 16, 0, 0);
}

// ---------------------------------------------------------------------------
// prep_w: per 64x64 tile of W: sigma = 1e-6+softplus(W_p);
//   - write transposed, XOR-swizzled bf16 W_mu and sigma^2 (GEMM B operands)
//   - write plain-layout bf16 sigma (for sim_max)
//   - atomicAdd row/col norm^2 partials, KLD partial
// ---------------------------------------------------------------------------
__global__ __launch_bounds__(256) void prep_w_kernel(
    const float* __restrict__ Wmu0, const float* __restrict__ Wp0,
    const float* __restrict__ Wmu1, const float* __restrict__ Wp1,
    const float* __restrict__ Wmu2, const float* __restrict__ Wp2,
    uint16_t* __restrict__ Wt, uint16_t* __restrict__ St2,
    uint16_t* __restrict__ Sg,
    float* __restrict__ row2, float* __restrict__ col2, float* __restrict__ kld) {
  const int layer = blockIdx.z;
  const int ni = (layer == 0) ? 1024 : 2048;
  const int no = (layer == 2) ? 1024 : 2048;
  if ((int)blockIdx.x >= (ni >> 6) || (int)blockIdx.y >= (no >> 6)) return;
  const float* Wmu = layer == 0 ? Wmu0 : (layer == 1 ? Wmu1 : Wmu2);
  const float* Wp  = layer == 0 ? Wp0  : (layer == 1 ? Wp1  : Wp2);
  const size_t wofs = layer == 0 ? 0 : (layer == 1 ? 2097152 : 6291456);
  uint16_t* wt = Wt + wofs;
  uint16_t* st = St2 + wofs;
  uint16_t* sgb = Sg + wofs;
  float* r2 = row2 + layer * 2048;
  float* c2 = col2 + layer * 2048;

  __shared__ uint16_t lmu[64][72];
  __shared__ uint16_t ls2[64][72];
  __shared__ float red[256];

  const int t = threadIdx.x;
  const int i0 = blockIdx.x * 64, j0 = blockIdx.y * 64;
  const int w = t >> 6, lane = t & 63;
  float colpart = 0.f, kpart = 0.f;
#pragma unroll
  for (int rep = 0; rep < 16; ++rep) {
    int il = rep * 4 + w;
    int jl = lane;
    size_t gi = (size_t)(i0 + il) * no + (j0 + jl);
    float mu = Wmu[gi], p = Wp[gi];
    float sg = softplus1(p);
    float s2 = sg * sg;
    kpart += 2.f * (LOG_P01 - logf(sg)) - 1.f + 100.f * s2 + 100.f * mu * mu;
    float rs = s2;
    for (int o = 32; o; o >>= 1) rs += __shfl_xor(rs, o, 64);
    if (lane == 0) atomicAdd(&r2[i0 + il], rs);
    colpart += s2;
    sgb[gi] = f2bf(sg);
    lmu[jl][il] = f2bf(mu);
    ls2[jl][il] = f2bf(s2);
  }
  red[t] = colpart;
  __syncthreads();
  if (t < 64) {
    float cs = red[t] + red[64 + t] + red[128 + t] + red[192 + t];
    atomicAdd(&c2[j0 + t], cs);
  }
  // transposed, swizzled write-out (16B chunks): row j, byte (k*2)^((j&7)<<4)
  const int Kb = ni * 2;
#pragma unroll
  for (int cc = 0; cc < 2; ++cc) {
    int c = cc * 256 + t;
    int nl = c >> 3, kc = c & 7;
    short8 vmu = *(const short8*)((const char*)&lmu[0][0] + nl * 144 + kc * 16);
    short8 vs2 = *(const short8*)((const char*)&ls2[0][0] + nl * 144 + kc * 16);
    size_t db = (size_t)(j0 + nl) * Kb + (((i0 * 2 + kc * 16)) ^ ((nl & 7) << 4));
    *(short8*)((char*)wt + db) = vmu;
    *(short8*)((char*)st + db) = vs2;
  }
  __syncthreads();
  red[t] = kpart;
  __syncthreads();
  for (int o = 128; o >= 1; o >>= 1) {
    if (t < o) red[t] += red[t + o];
    __syncthreads();
  }
  if (t == 0) atomicAdd(kld, 0.5f * red[0]);
}

// ---------------------------------------------------------------------------
// prep_x: bf16(x), bf16(x*x) into swizzled [8192][1024] layout
// ---------------------------------------------------------------------------
__global__ __launch_bounds__(256) void prep_x_kernel(const float* __restrict__ x,
                                                     uint16_t* __restrict__ Ah,
                                                     uint16_t* __restrict__ Ah2) {
  size_t c = (size_t)blockIdx.x * 256 + threadIdx.x;  // 8-elem chunk
  size_t gidx = c * 8;
  if (gidx >= (size_t)8192 * 1024) return;
  int m = (int)(gidx >> 10);
  int k0 = (int)(gidx & 1023);
  const float4* xp = (const float4*)(x + gidx);
  float4 a = xp[0], b = xp[1];
  float vals[8] = {a.x, a.y, a.z, a.w, b.x, b.y, b.z, b.w};
  union { uint16_t u[8]; short8 v; } ph, ph2;
#pragma unroll
  for (int e = 0; e < 8; ++e) {
    float f = vals[e];
    ph.u[e] = f2bf(f);
    ph2.u[e] = f2bf(f * f);
  }
  size_t ob = (size_t)m * 2048 + ((k0 * 2) ^ ((m & 7) << 4));
  *(short8*)((char*)Ah + ob) = ph.v;
  *(short8*)((char*)Ah2 + ob) = ph2.v;
}

// ---------------------------------------------------------------------------
// prep_bias: bias[n] = b_mu + softplus(b_p)*eps_b ; bias KLD
// ---------------------------------------------------------------------------
__global__ __launch_bounds__(256) void prep_bias_kernel(
    const float* bmu0, const float* bp0, const float* eb0,
    const float* bmu1, const float* bp1, const float* eb1,
    const float* bmu2, const float* bp2, const float* eb2,
    float* __restrict__ bias, float* __restrict__ kld) {
  int t = blockIdx.x * 256 + threadIdx.x;
  float kpart = 0.f;
  if (t < 5120) {
    int layer = t < 2048 ? 0 : (t < 4096 ? 1 : 2);
    int n = t - (layer == 0 ? 0 : (layer == 1 ? 2048 : 4096));
    const float* bmu = layer == 0 ? bmu0 : (layer == 1 ? bmu1 : bmu2);
    const float* bp  = layer == 0 ? bp0  : (layer == 1 ? bp1  : bp2);
    const float* eb  = layer == 0 ? eb0  : (layer == 1 ? eb1  : eb2);
    float mu = bmu[n], p = bp[n], e = eb[n];
    float sg = softplus1(p);
    bias[layer * 2048 + n] = mu + sg * e;
    kpart = 0.5f * (2.f * (LOG_P01 - logf(sg)) - 1.f + 100.f * sg * sg + 100.f * mu * mu);
  }
  for (int o = 32; o; o >>= 1) kpart += __shfl_xor(kpart, o, 64);
  if ((threadIdx.x & 63) == 0) atomicAdd(kld, kpart);
}

// ---------------------------------------------------------------------------
// sim_max: single linear grid-stride pass over concatenated sim (320MB).
// ---------------------------------------------------------------------------
__global__ __launch_bounds__(256) void sim_max_kernel(
    const float* __restrict__ s0, const float* __restrict__ s1,
    const float* __restrict__ s2, const uint16_t* __restrict__ Sg,
    float* __restrict__ partial) {
  __shared__ int lmax[30];
  if (threadIdx.x < 30) lmax[threadIdx.x] = 0;
  __syncthreads();
  const size_t stride = (size_t)gridDim.x * 256;
  for (size_t c = (size_t)blockIdx.x * 256 + threadIdx.x; c < 20971520; c += stride) {
    const float* sp; size_t within; const uint16_t* sgp; int slot_base, shift;
    if (c < 5242880)       { sp = s0; within = c;            sgp = Sg;           slot_base = 0;  shift = 19; }
    else if (c < 15728640) { sp = s1; within = c - 5242880;  sgp = Sg + 2097152; slot_base = 10; shift = 20; }
    else                   { sp = s2; within = c - 15728640; sgp = Sg + 6291456; slot_base = 20; shift = 19; }
    int s = (int)(within >> shift);
    size_t idx = within - ((size_t)s << shift);
    float4 v = ((const float4*)sp)[within];
    ushort4 sv = *(const ushort4*)(sgp + idx * 4);
    float m = fmaxf(fmaxf(v.x * bf2f(sv.x), v.y * bf2f(sv.y)),
                    fmaxf(v.z * bf2f(sv.z), v.w * bf2f(sv.w)));
    for (int o = 32; o; o >>= 1) m = fmaxf(m, __shfl_xor(m, o, 64));
    if ((threadIdx.x & 63) == 0)
      atomicMax(&lmax[slot_base + s], __float_as_int(fmaxf(m, 0.f)));
  }
  __syncthreads();
  if (threadIdx.x < 30)
    partial[threadIdx.x * 2048 + blockIdx.x] = __int_as_float(lmax[threadIdx.x]);
}

// ---------------------------------------------------------------------------
// gemm_nt (3 layers, SYMMETRIC): C = R @ R^T. Blocks with by<bx exit; by>bx
// write C and C^T; diagonal writes once (deterministic, no duplicate writes).
// ---------------------------------------------------------------------------
__global__ __launch_bounds__(256, 2) void gemm_nt_kernel(
    const uint16_t* __restrict__ Wt, float* __restrict__ Bmat) {
  const int layer = blockIdx.z;
  const int K = (layer == 0) ? 1024 : 2048;
  const int N = (layer == 2) ? 1024 : 2048;
  if ((int)blockIdx.x >= (N >> 7) || (int)blockIdx.y >= (N >> 7)) return;
  if (blockIdx.y < blockIdx.x) return;  // symmetric: keep by >= bx
  const uint16_t* R = Wt + (layer == 0 ? 0 : (layer == 1 ? 2097152 : 6291456));
  float* C = Bmat + (layer == 0 ? 0 : (layer == 1 ? 4194304 : 8388608));

  __shared__ uint16_t lds[16384];  // 32KB: A-tile [128][64] | B-tile [128][64]
  const int t = threadIdx.x;
  const int w = t >> 6, lane = t & 63;
  const int m0 = blockIdx.y * 128, n0 = blockIdx.x * 128;
  const int wm = (w >> 1) * 64, wn = (w & 1) * 64;
  const size_t Kb = (size_t)K * 2;

  f32x4 zero = {0.f, 0.f, 0.f, 0.f};
  f32x4 acc[4][4];
#pragma unroll
  for (int i = 0; i < 4; ++i)
#pragma unroll
    for (int j = 0; j < 4; ++j) acc[i][j] = zero;

  const int rb = ((w < 2) ? m0 : n0) + (w & 1) * 64;
  const char* gsrc = (const char*)R + (size_t)rb * Kb;
  uint16_t* ltile = lds + (w < 2 ? 0 : 8192) + (w & 1) * 4096;
  const int lrow = lane >> 3;
  const int lcol = (lane & 7) * 16;

  int offA[4][2], offB[4][2];
#pragma unroll
  for (int i = 0; i < 4; ++i) {
    int rowa = wm + i * 16 + (lane & 15);
    int rowb = wn + i * 16 + (lane & 15);
    int kp = (lane >> 4) << 4;
#pragma unroll
    for (int kk = 0; kk < 2; ++kk) {
      offA[i][kk] = (rowa << 7) + (((kk << 6) + kp) ^ ((rowa & 7) << 4));
      offB[i][kk] = (rowb << 7) + (((kk << 6) + kp) ^ ((rowb & 7) << 4));
    }
  }
  const char* ldsc = (const char*)lds;
  const int nkt = K >> 6;
  for (int kt = 0; kt < nkt; ++kt) {
    const char* gb = gsrc + (size_t)kt * 128;
#pragma unroll
    for (int r = 0; r < 8; ++r) {
      gload16(gb + (size_t)(r * 8 + lrow) * Kb + lcol, ltile + r * 512);
    }
    __syncthreads();
#pragma unroll
    for (int kk = 0; kk < 2; ++kk) {
      bf16x8 af[4], bfr[4];
#pragma unroll
      for (int i = 0; i < 4; ++i) {
        af[i]  = *(const bf16x8*)(ldsc + offA[i][kk]);
        bfr[i] = *(const bf16x8*)(ldsc + 16384 + offB[i][kk]);
      }
#pragma unroll
      for (int i = 0; i < 4; ++i)
#pragma unroll
        for (int j = 0; j < 4; ++j)
          acc[i][j] = __builtin_amdgcn_mfma_f32_16x16x32_bf16(af[i], bfr[j], acc[i][j], 0, 0, 0);
    }
    __syncthreads();
  }
  const int mirror = (blockIdx.y > blockIdx.x);
#pragma unroll
  for (int j = 0; j < 4; ++j) {
    int n = n0 + wn + j * 16 + (lane & 15);
#pragma unroll
    for (int i = 0; i < 4; ++i) {
      int mb = m0 + wm + i * 16 + ((lane >> 4) << 2);
      f32x4 a = acc[i][j];
#pragma unroll
      for (int r = 0; r < 4; ++r) {
        C[(size_t)(mb + r) * N + n] = a[r];
        if (mirror) C[(size_t)n * N + (mb + r)] = a[r];
      }
    }
  }
}

// ---------------------------------------------------------------------------
// v1: v = W^T u0 per layer — wave per row of Wt (bf16 swizzled), fp32 accum
// ---------------------------------------------------------------------------
__global__ __launch_bounds__(256) void v1_kernel(const uint16_t* __restrict__ Wt,
                                                 const float* u00, const float* u01,
                                                 const float* u02,
                                                 float* __restrict__ vout) {
  int gw = (blockIdx.x * 256 + threadIdx.x) >> 6;  // 0..5119
  int lane = threadIdx.x & 63;
  int layer = gw < 2048 ? 0 : (gw < 4096 ? 1 : 2);
  int j = gw - (layer == 0 ? 0 : (layer == 1 ? 2048 : 4096));
  int ni = layer == 0 ? 1024 : 2048;
  const uint16_t* row = Wt + (layer == 0 ? 0 : (layer == 1 ? 2097152 : 6291456)) + (size_t)j * ni;
  const float* u0 = layer == 0 ? u00 : (layer == 1 ? u01 : u02);
  int nc = ni >> 3;
  float part = 0.f;
  for (int c = lane; c < nc; c += 64) {
    int bo = (c * 16) ^ ((j & 7) << 4);
    short8 v = *(const short8*)((const char*)row + bo);
    const float4* up = (const float4*)(u0 + c * 8);
    float4 a = up[0], b = up[1];
    float us[8] = {a.x, a.y, a.z, a.w, b.x, b.y, b.z, b.w};
#pragma unroll
    for (int e = 0; e < 8; ++e) part += bf2f((uint16_t)((short*)&v)[e]) * us[e];
  }
  for (int o = 32; o; o >>= 1) part += __shfl_xor(part, o, 64);
  if (lane == 0) vout[layer * 2048 + j] = part;
}

// ---------------------------------------------------------------------------
// bmv: vout = B vin for all 3 layers (wave per row, fp32)
// ---------------------------------------------------------------------------
__global__ __launch_bounds__(256) void bmv_kernel(const float* __restrict__ Bm,
                                                  const float* __restrict__ vin,
                                                  float* __restrict__ vout) {
  int gw = (blockIdx.x * 256 + threadIdx.x) >> 6;  // 0..5119
  int lane = threadIdx.x & 63;
  int layer = gw < 2048 ? 0 : (gw < 4096 ? 1 : 2);
  int r = gw - (layer == 0 ? 0 : (layer == 1 ? 2048 : 4096));
  int n = layer == 2 ? 1024 : 2048;
  const float* row = Bm + (layer == 0 ? 0 : (layer == 1 ? 4194304 : 8388608)) + (size_t)r * n;
  const float* v = vin + layer * 2048;
  float part = 0.f;
  for (int c = lane * 4; c < n; c += 256) {
    float4 w4 = *(const float4*)(row + c);
    float4 v4 = *(const float4*)(v + c);
    part += w4.x * v4.x + w4.y * v4.y + w4.z * v4.z + w4.w * v4.w;
  }
  for (int o = 32; o; o >>= 1) part += __shfl_xor(part, o, 64);
  if (lane == 0) vout[layer * 2048 + r] = part;
}

// ---------------------------------------------------------------------------
// gemm_single: m97-structure single GEMM (3 blocks/CU target), 128x128 tile,
// BK=64, 32KB LDS, 2 barriers/K-tile, proven swizzle (gemm_nt main loop).
// is_s=1: O = sqrt(max(A2@B2,0)) -> sd staged into Oh2's element slots (bf16,
//   next-layer-input swizzled layout) or Oy (fp32, last layer).
// is_s=0: O = A@B + sd*eps + bias; relu+pack (non-last) or fp32 y (last).
//   sd read back from the SAME slot the s-pass wrote (same thread reads then
//   overwrites its own element -> no hazard; launches are stream-ordered).
// ---------------------------------------------------------------------------
__global__ __launch_bounds__(256, 3) void gemm_single_kernel(
    const uint16_t* __restrict__ Ab, const uint16_t* __restrict__ Bb,
    const float* __restrict__ eps, const float* __restrict__ bias,
    uint16_t* __restrict__ Oh, uint16_t* __restrict__ Oh2,
    float* __restrict__ Oy, int K, int N, int last, int is_s, int nwgx) {
  __shared__ uint16_t lds[16384];  // 32KB: A-tile [128][64] | B-tile [128][64]
  const int t = threadIdx.x;
  const int w = t >> 6, lane = t & 63;

  // T1: bijective XCD swizzle (grid always % 8 == 0 here)
  const int nwg = gridDim.x;
  const int cpx = nwg >> 3;
  const int bid = blockIdx.x;
  const int logical = (bid & 7) * cpx + (bid >> 3);
  const int bx = logical % nwgx, by = logical / nwgx;

  const int m0 = by * 128, n0 = bx * 128;
  const int wm = (w >> 1) * 64, wn = (w & 1) * 64;
  const size_t Kb = (size_t)K * 2;

  f32x4 zero = {0.f, 0.f, 0.f, 0.f};
  f32x4 acc[4][4];
#pragma unroll
  for (int i = 0; i < 4; ++i)
#pragma unroll
    for (int j = 0; j < 4; ++j) acc[i][j] = zero;

  const int rb = ((w < 2) ? m0 : n0) + (w & 1) * 64;
  const char* gsrc = (const char*)((w < 2) ? Ab : Bb) + (size_t)rb * Kb;
  uint16_t* ltile = lds + (w < 2 ? 0 : 8192) + (w & 1) * 4096;
  const int lrow = lane >> 3;
  const int lcol = (lane & 7) * 16;

  int offA[4][2], offB[4][2];
#pragma unroll
  for (int i = 0; i < 4; ++i) {
    int rowa = wm + i * 16 + (lane & 15);
    int rowb = wn + i * 16 + (lane & 15);
    int kp = (lane >> 4) << 4;
#pragma unroll
    for (int kk = 0; kk < 2; ++kk) {
      offA[i][kk] = (rowa << 7) + (((kk << 6) + kp) ^ ((rowa & 7) << 4));
      offB[i][kk] = (rowb << 7) + (((kk << 6) + kp) ^ ((rowb & 7) << 4));
    }
  }
  const char* ldsc = (const char*)lds;
  const int nkt = K >> 6;
  for (int kt = 0; kt < nkt; ++kt) {
    const char* gb = gsrc + (size_t)kt * 128;
#pragma unroll
    for (int r = 0; r < 8; ++r) {
      gload16(gb + (size_t)(r * 8 + lrow) * Kb + lcol, ltile + r * 512);
    }
    __syncthreads();
#pragma unroll
    for (int kk = 0; kk < 2; ++kk) {
      bf16x8 af[4], bfr[4];
#pragma unroll
      for (int i = 0; i < 4; ++i) {
        af[i]  = *(const bf16x8*)(ldsc + offA[i][kk]);
        bfr[i] = *(const bf16x8*)(ldsc + 16384 + offB[i][kk]);
      }
#pragma unroll
      for (int i = 0; i < 4; ++i)
#pragma unroll
        for (int j = 0; j < 4; ++j)
          acc[i][j] = __builtin_amdgcn_mfma_f32_16x16x32_bf16(af[i], bfr[j], acc[i][j], 0, 0, 0);
    }
    __syncthreads();
  }

  // epilogue
  const int nstrb = N * 2;
#pragma unroll
  for (int j = 0; j < 4; ++j) {
    int n = n0 + wn + j * 16 + (lane & 15);
    float bn = is_s ? 0.f : bias[n];
#pragma unroll
    for (int i = 0; i < 4; ++i) {
      int mb = m0 + wm + i * 16 + ((lane >> 4) << 2);
      f32x4 a = acc[i][j];
#pragma unroll
      for (int r = 0; r < 4; ++r) {
        int m = mb + r;
        size_t ob = (size_t)m * nstrb + ((n * 2) ^ ((m & 7) << 4));
        if (is_s) {
          float sd = sqrtf(fmaxf(a[r], 0.f));
          if (last) Oy[(size_t)m * N + n] = sd;
          else      *(uint16_t*)((char*)Oh2 + ob) = f2bf(sd);
        } else {
          float sd = last ? Oy[(size_t)m * N + n]
                          : bf2f(*(const uint16_t*)((const char*)Oh2 + ob));
          float val = a[r] + sd * eps[(size_t)m * N + n] + bn;
          if (last) {
            Oy[(size_t)m * N + n] = val;
          } else {
            float h = fmaxf(val, 0.f);
            *(uint16_t*)((char*)Oh + ob) = f2bf(h);
            *(uint16_t*)((char*)Oh2 + ob) = f2bf(h * h);
          }
        }
      }
    }
  }
}

// ---------------------------------------------------------------------------
// finalize: reduce sim partials; tkld, tlip.
// sigma = sqrt(dot(v10,Bv10)/dot(v10,v10))
// ---------------------------------------------------------------------------
__device__ __forceinline__ float block_red(float v, int is_max, float* red) {
  int t = threadIdx.x;
  red[t] = v;
  __syncthreads();
  for (int o = 128; o >= 1; o >>= 1) {
    if (t < o) red[t] = is_max ? fmaxf(red[t], red[t + o]) : (red[t] + red[t + o]);
    __syncthreads();
  }
  float r = red[0];
  __syncthreads();
  return r;
}

__global__ __launch_bounds__(256) void finalize_kernel(const float* __restrict__ acc,
                                                       const float* __restrict__ v10,
                                                       const float* __restrict__ wv,
                                                       const float* __restrict__ partial,
                                                       float* __restrict__ out2) {
  __shared__ float red[256];
  __shared__ float smax[30];
  int t = threadIdx.x;
  int w = t >> 6, lane = t & 63;
  for (int sl = w; sl < 30; sl += 4) {
    float m = 0.f;
    for (int b = lane; b < 2048; b += 64) m = fmaxf(m, partial[sl * 2048 + b]);
    for (int o = 32; o; o >>= 1) m = fmaxf(m, __shfl_xor(m, o, 64));
    if (lane == 0) smax[sl] = m;
  }
  __syncthreads();
  float tlip = 0.f;
  for (int layer = 0; layer < 3; ++layer) {
    int ni = layer == 0 ? 1024 : 2048;
    int no = layer == 2 ? 1024 : 2048;
    float mr = 0.f, mc = 0.f, s2n = 0.f, s2d = 0.f;
    for (int i = t; i < ni; i += 256) mr = fmaxf(mr, acc[64 + layer * 2048 + i]);
    for (int j = t; j < no; j += 256) mc = fmaxf(mc, acc[6208 + layer * 2048 + j]);
    for (int j = t; j < no; j += 256) {
      float v = v10[layer * 2048 + j], wv_ = wv[layer * 2048 + j];
      s2n += v * wv_;
      s2d += v * v;
    }
    mr = block_red(mr, 1, red);
    mc = block_red(mc, 1, red);
    s2n = block_red(s2n, 0, red);
    s2d = block_red(s2d, 0, red);
    if (t == 0) {
      float sm = 0.f;
      for (int s = 0; s < 10; ++s) sm += smax[layer * 10 + s];
      sm *= 0.1f;
      float sigma = sqrtf(s2n / s2d);
      float res = sqrtf(mr) + sqrtf(mc);
      float l = res + sm + sigma;
      tlip += l * l;
    }
  }
  if (t == 0) {
    out2[0] = acc[0];
    out2[1] = tlip;
  }
}

// ---------------------------------------------------------------------------
extern "C" void kernel_launch(void* const* d_in, const int* in_sizes, int n_in,
                              void* d_out, int out_size, void* d_ws, size_t ws_size,
                              hipStream_t stream) {
  (void)in_sizes; (void)n_in; (void)out_size; (void)ws_size;
  const float* x = (const float*)d_in[0];
  const float* Wmu[3] = {(const float*)d_in[1], (const float*)d_in[9],  (const float*)d_in[17]};
  const float* Wp[3]  = {(const float*)d_in[2], (const float*)d_in[10], (const float*)d_in[18]};
  const float* bmu[3] = {(const float*)d_in[3], (const float*)d_in[11], (const float*)d_in[19]};
  const float* bp[3]  = {(const float*)d_in[4], (const float*)d_in[12], (const float*)d_in[20]};
  const float* epsw[3]= {(const float*)d_in[5], (const float*)d_in[13], (const float*)d_in[21]};
  const float* epsb[3]= {(const float*)d_in[6], (const float*)d_in[14], (const float*)d_in[22]};
  const float* u0[3]  = {(const float*)d_in[7], (const float*)d_in[15], (const float*)d_in[23]};
  const float* sim[3] = {(const float*)d_in[8], (const float*)d_in[16], (const float*)d_in[24]};

  char* ws = (char*)d_ws;
  uint16_t* A0h  = (uint16_t*)(ws);
  uint16_t* A0h2 = (uint16_t*)(ws + 33554432);
  uint16_t* A1h  = (uint16_t*)(ws + 67108864);
  uint16_t* A1h2 = (uint16_t*)(ws + 100663296);
  float*    Bmat = (float*)(ws + 67108864);     // aliases A1h: dead before gemm1
  uint16_t* Sgbf = (uint16_t*)(ws + 104857600); // aliases A1h2 tail: dead before gemm1
  uint16_t* Wt   = (uint16_t*)(ws + 134217728);
  uint16_t* St2  = (uint16_t*)(ws + 150994944);
  float* bias    = (float*)(ws + 167772160);
  float* pbuf0   = (float*)(ws + 167796736);
  float* pbuf1   = (float*)(ws + 167821312);
  float* acc     = (float*)(ws + 167845888);
  float* partial = (float*)(ws + 167895296);    // 30*2048 floats
  // acc layout: [0] kld | [64..6207] row2 | [6208..12351] col2

  hipMemsetAsync(ws + 167845888, 0, 49408, stream);

  prep_w_kernel<<<dim3(32, 32, 3), 256, 0, stream>>>(
      Wmu[0], Wp[0], Wmu[1], Wp[1], Wmu[2], Wp[2], Wt, St2, Sgbf, acc + 64, acc + 6208, acc);
  prep_x_kernel<<<4096, 256, 0, stream>>>(x, A0h, A0h2);
  prep_bias_kernel<<<20, 256, 0, stream>>>(
      bmu[0], bp[0], epsb[0], bmu[1], bp[1], epsb[1], bmu[2], bp[2], epsb[2], bias, acc);
  sim_max_kernel<<<2048, 256, 0, stream>>>(sim[0], sim[1], sim[2], Sgbf, partial);

  // B = W^T W per layer (symmetric: ~half the blocks), one launch
  gemm_nt_kernel<<<dim3(16, 16, 3), 256, 0, stream>>>(Wt, Bmat);

  // v1 = W^T u0 ; then v_{k+1} = B v_k ; v10 in pbuf1, w = B v10 in pbuf0
  v1_kernel<<<1280, 256, 0, stream>>>(Wt, u0[0], u0[1], u0[2], pbuf0);
  for (int it = 0; it < 10; ++it) {
    const float* vin = (it & 1) ? pbuf1 : pbuf0;
    float* vout = (it & 1) ? pbuf0 : pbuf1;
    bmv_kernel<<<1280, 256, 0, stream>>>(Bmat, vin, vout);
  }

  float* y = (float*)d_out;
  // Layer 0: sd -> A1h2 slots, then mu reads sd, writes h->A1h, h^2->A1h2
  gemm_single_kernel<<<1024, 256, 0, stream>>>(
      A0h2, St2, epsw[0], bias, A1h, A1h2, nullptr, 1024, 2048, 0, 1, 16);
  gemm_single_kernel<<<1024, 256, 0, stream>>>(
      A0h, Wt, epsw[0], bias, A1h, A1h2, nullptr, 1024, 2048, 0, 0, 16);
  // Layer 1: sd -> A0h2 slots, mu writes h->A0h, h^2->A0h2
  gemm_single_kernel<<<1024, 256, 0, stream>>>(
      A1h2, St2 + 2097152, epsw[1], bias + 2048, A0h, A0h2, nullptr, 2048, 2048, 0, 1, 16);
  gemm_single_kernel<<<1024, 256, 0, stream>>>(
      A1h, Wt + 2097152, epsw[1], bias + 2048, A0h, A0h2, nullptr, 2048, 2048, 0, 0, 16);
  // Layer 2 (last): sd -> y (fp32), mu reads y, writes final y
  gemm_single_kernel<<<512, 256, 0, stream>>>(
      A0h2, St2 + 6291456, epsw[2], bias + 4096, nullptr, nullptr, y, 2048, 1024, 1, 1, 8);
  gemm_single_kernel<<<512, 256, 0, stream>>>(
      A0h, Wt + 6291456, epsw[2], bias + 4096, nullptr, nullptr, y, 2048, 1024, 1, 0, 8);

  finalize_kernel<<<1, 256, 0, stream>>>(acc, pbuf1, pbuf0, partial, y + 8388608);
}

// Round 11
// 851.269 us; speedup vs baseline: 1.1192x; 1.1192x over previous
//
#include <hip/hip_runtime.h>
#include <stdint.h>

typedef __attribute__((ext_vector_type(8))) __bf16 bf16x8;
typedef __attribute__((ext_vector_type(8))) short short8;
typedef __attribute__((ext_vector_type(4))) float f32x4;

#define LOG_P01 (-2.302585093f)   // log(0.1)

__device__ __forceinline__ uint16_t f2bf(float f) {
  union { float f; uint32_t u; } v; v.f = f;
  uint32_t r = (v.u + 0x7fffu + ((v.u >> 16) & 1u)) >> 16;
  return (uint16_t)r;
}
__device__ __forceinline__ float bf2f(uint16_t u) {
  union { uint32_t u; float f; } v; v.u = ((uint32_t)u) << 16;
  return v.f;
}
__device__ __forceinline__ float softplus1(float x) { return 1e-6f + log1pf(expf(x)); }

__device__ __forceinline__ void gload16(const void* g, void* l) {
  __builtin_amdgcn_global_load_lds(
      (__attribute__((address_space(1))) void*)(g),
      (__attribute__((address_space(3))) void*)(l), 16, 0, 0);
}

// ---------------------------------------------------------------------------
// prep_w: per 64x64 tile of W: sigma = 1e-6+softplus(W_p);
//   - write transposed, XOR-swizzled bf16 W_mu and sigma^2 (GEMM B operands)
//   - write plain-layout bf16 sigma (for sim_max)
//   - atomicAdd row/col norm^2 partials, KLD partial
// ---------------------------------------------------------------------------
__global__ __launch_bounds__(256) void prep_w_kernel(
    const float* __restrict__ Wmu0, const float* __restrict__ Wp0,
    const float* __restrict__ Wmu1, const float* __restrict__ Wp1,
    const float* __restrict__ Wmu2, const float* __restrict__ Wp2,
    uint16_t* __restrict__ Wt, uint16_t* __restrict__ St2,
    uint16_t* __restrict__ Sg,
    float* __restrict__ row2, float* __restrict__ col2, float* __restrict__ kld) {
  const int layer = blockIdx.z;
  const int ni = (layer == 0) ? 1024 : 2048;
  const int no = (layer == 2) ? 1024 : 2048;
  if ((int)blockIdx.x >= (ni >> 6) || (int)blockIdx.y >= (no >> 6)) return;
  const float* Wmu = layer == 0 ? Wmu0 : (layer == 1 ? Wmu1 : Wmu2);
  const float* Wp  = layer == 0 ? Wp0  : (layer == 1 ? Wp1  : Wp2);
  const size_t wofs = layer == 0 ? 0 : (layer == 1 ? 2097152 : 6291456);
  uint16_t* wt = Wt + wofs;
  uint16_t* st = St2 + wofs;
  uint16_t* sgb = Sg + wofs;
  float* r2 = row2 + layer * 2048;
  float* c2 = col2 + layer * 2048;

  __shared__ uint16_t lmu[64][72];
  __shared__ uint16_t ls2[64][72];
  __shared__ float red[256];

  const int t = threadIdx.x;
  const int i0 = blockIdx.x * 64, j0 = blockIdx.y * 64;
  const int w = t >> 6, lane = t & 63;
  float colpart = 0.f, kpart = 0.f;
#pragma unroll
  for (int rep = 0; rep < 16; ++rep) {
    int il = rep * 4 + w;
    int jl = lane;
    size_t gi = (size_t)(i0 + il) * no + (j0 + jl);
    float mu = Wmu[gi], p = Wp[gi];
    float sg = softplus1(p);
    float s2 = sg * sg;
    kpart += 2.f * (LOG_P01 - logf(sg)) - 1.f + 100.f * s2 + 100.f * mu * mu;
    float rs = s2;
    for (int o = 32; o; o >>= 1) rs += __shfl_xor(rs, o, 64);
    if (lane == 0) atomicAdd(&r2[i0 + il], rs);
    colpart += s2;
    sgb[gi] = f2bf(sg);
    lmu[jl][il] = f2bf(mu);
    ls2[jl][il] = f2bf(s2);
  }
  red[t] = colpart;
  __syncthreads();
  if (t < 64) {
    float cs = red[t] + red[64 + t] + red[128 + t] + red[192 + t];
    atomicAdd(&c2[j0 + t], cs);
  }
  // transposed, swizzled write-out (16B chunks): row j, byte (k*2)^((j&7)<<4)
  const int Kb = ni * 2;
#pragma unroll
  for (int cc = 0; cc < 2; ++cc) {
    int c = cc * 256 + t;
    int nl = c >> 3, kc = c & 7;
    short8 vmu = *(const short8*)((const char*)&lmu[0][0] + nl * 144 + kc * 16);
    short8 vs2 = *(const short8*)((const char*)&ls2[0][0] + nl * 144 + kc * 16);
    size_t db = (size_t)(j0 + nl) * Kb + (((i0 * 2 + kc * 16)) ^ ((nl & 7) << 4));
    *(short8*)((char*)wt + db) = vmu;
    *(short8*)((char*)st + db) = vs2;
  }
  __syncthreads();
  red[t] = kpart;
  __syncthreads();
  for (int o = 128; o >= 1; o >>= 1) {
    if (t < o) red[t] += red[t + o];
    __syncthreads();
  }
  if (t == 0) atomicAdd(kld, 0.5f * red[0]);
}

// ---------------------------------------------------------------------------
// prep_x: bf16(x), bf16(x*x) into swizzled [8192][1024] layout
// ---------------------------------------------------------------------------
__global__ __launch_bounds__(256) void prep_x_kernel(const float* __restrict__ x,
                                                     uint16_t* __restrict__ Ah,
                                                     uint16_t* __restrict__ Ah2) {
  size_t c = (size_t)blockIdx.x * 256 + threadIdx.x;  // 8-elem chunk
  size_t gidx = c * 8;
  if (gidx >= (size_t)8192 * 1024) return;
  int m = (int)(gidx >> 10);
  int k0 = (int)(gidx & 1023);
  const float4* xp = (const float4*)(x + gidx);
  float4 a = xp[0], b = xp[1];
  float vals[8] = {a.x, a.y, a.z, a.w, b.x, b.y, b.z, b.w};
  union { uint16_t u[8]; short8 v; } ph, ph2;
#pragma unroll
  for (int e = 0; e < 8; ++e) {
    float f = vals[e];
    ph.u[e] = f2bf(f);
    ph2.u[e] = f2bf(f * f);
  }
  size_t ob = (size_t)m * 2048 + ((k0 * 2) ^ ((m & 7) << 4));
  *(short8*)((char*)Ah + ob) = ph.v;
  *(short8*)((char*)Ah2 + ob) = ph2.v;
}

// ---------------------------------------------------------------------------
// prep_bias: bias[n] = b_mu + softplus(b_p)*eps_b ; bias KLD
// ---------------------------------------------------------------------------
__global__ __launch_bounds__(256) void prep_bias_kernel(
    const float* bmu0, const float* bp0, const float* eb0,
    const float* bmu1, const float* bp1, const float* eb1,
    const float* bmu2, const float* bp2, const float* eb2,
    float* __restrict__ bias, float* __restrict__ kld) {
  int t = blockIdx.x * 256 + threadIdx.x;
  float kpart = 0.f;
  if (t < 5120) {
    int layer = t < 2048 ? 0 : (t < 4096 ? 1 : 2);
    int n = t - (layer == 0 ? 0 : (layer == 1 ? 2048 : 4096));
    const float* bmu = layer == 0 ? bmu0 : (layer == 1 ? bmu1 : bmu2);
    const float* bp  = layer == 0 ? bp0  : (layer == 1 ? bp1  : bp2);
    const float* eb  = layer == 0 ? eb0  : (layer == 1 ? eb1  : eb2);
    float mu = bmu[n], p = bp[n], e = eb[n];
    float sg = softplus1(p);
    bias[layer * 2048 + n] = mu + sg * e;
    kpart = 0.5f * (2.f * (LOG_P01 - logf(sg)) - 1.f + 100.f * sg * sg + 100.f * mu * mu);
  }
  for (int o = 32; o; o >>= 1) kpart += __shfl_xor(kpart, o, 64);
  if ((threadIdx.x & 63) == 0) atomicAdd(kld, kpart);
}

// ---------------------------------------------------------------------------
// sim_max: single linear grid-stride pass over concatenated sim (320MB).
// ---------------------------------------------------------------------------
__global__ __launch_bounds__(256) void sim_max_kernel(
    const float* __restrict__ s0, const float* __restrict__ s1,
    const float* __restrict__ s2, const uint16_t* __restrict__ Sg,
    float* __restrict__ partial) {
  __shared__ int lmax[30];
  if (threadIdx.x < 30) lmax[threadIdx.x] = 0;
  __syncthreads();
  const size_t stride = (size_t)gridDim.x * 256;
  for (size_t c = (size_t)blockIdx.x * 256 + threadIdx.x; c < 20971520; c += stride) {
    const float* sp; size_t within; const uint16_t* sgp; int slot_base, shift;
    if (c < 5242880)       { sp = s0; within = c;            sgp = Sg;           slot_base = 0;  shift = 19; }
    else if (c < 15728640) { sp = s1; within = c - 5242880;  sgp = Sg + 2097152; slot_base = 10; shift = 20; }
    else                   { sp = s2; within = c - 15728640; sgp = Sg + 6291456; slot_base = 20; shift = 19; }
    int s = (int)(within >> shift);
    size_t idx = within - ((size_t)s << shift);
    float4 v = ((const float4*)sp)[within];
    ushort4 sv = *(const ushort4*)(sgp + idx * 4);
    float m = fmaxf(fmaxf(v.x * bf2f(sv.x), v.y * bf2f(sv.y)),
                    fmaxf(v.z * bf2f(sv.z), v.w * bf2f(sv.w)));
    for (int o = 32; o; o >>= 1) m = fmaxf(m, __shfl_xor(m, o, 64));
    if ((threadIdx.x & 63) == 0)
      atomicMax(&lmax[slot_base + s], __float_as_int(fmaxf(m, 0.f)));
  }
  __syncthreads();
  if (threadIdx.x < 30)
    partial[threadIdx.x * 2048 + blockIdx.x] = __int_as_float(lmax[threadIdx.x]);
}

// ---------------------------------------------------------------------------
// gemm_nt (3 layers, SYMMETRIC): C = R @ R^T, bf16 output (feeds bmv only).
// Blocks with by<bx exit; by>bx write C and C^T; diagonal writes once.
// ---------------------------------------------------------------------------
__global__ __launch_bounds__(256, 2) void gemm_nt_kernel(
    const uint16_t* __restrict__ Wt, uint16_t* __restrict__ Bmat) {
  const int layer = blockIdx.z;
  const int K = (layer == 0) ? 1024 : 2048;
  const int N = (layer == 2) ? 1024 : 2048;
  if ((int)blockIdx.x >= (N >> 7) || (int)blockIdx.y >= (N >> 7)) return;
  if (blockIdx.y < blockIdx.x) return;  // symmetric: keep by >= bx
  const uint16_t* R = Wt + (layer == 0 ? 0 : (layer == 1 ? 2097152 : 6291456));
  uint16_t* C = Bmat + (layer == 0 ? 0 : (layer == 1 ? 4194304 : 8388608));

  __shared__ uint16_t lds[16384];  // 32KB: A-tile [128][64] | B-tile [128][64]
  const int t = threadIdx.x;
  const int w = t >> 6, lane = t & 63;
  const int m0 = blockIdx.y * 128, n0 = blockIdx.x * 128;
  const int wm = (w >> 1) * 64, wn = (w & 1) * 64;
  const size_t Kb = (size_t)K * 2;

  f32x4 zero = {0.f, 0.f, 0.f, 0.f};
  f32x4 acc[4][4];
#pragma unroll
  for (int i = 0; i < 4; ++i)
#pragma unroll
    for (int j = 0; j < 4; ++j) acc[i][j] = zero;

  const int rb = ((w < 2) ? m0 : n0) + (w & 1) * 64;
  const char* gsrc = (const char*)R + (size_t)rb * Kb;
  uint16_t* ltile = lds + (w < 2 ? 0 : 8192) + (w & 1) * 4096;
  const int lrow = lane >> 3;
  const int lcol = (lane & 7) * 16;

  int offA[4][2], offB[4][2];
#pragma unroll
  for (int i = 0; i < 4; ++i) {
    int rowa = wm + i * 16 + (lane & 15);
    int rowb = wn + i * 16 + (lane & 15);
    int kp = (lane >> 4) << 4;
#pragma unroll
    for (int kk = 0; kk < 2; ++kk) {
      offA[i][kk] = (rowa << 7) + (((kk << 6) + kp) ^ ((rowa & 7) << 4));
      offB[i][kk] = (rowb << 7) + (((kk << 6) + kp) ^ ((rowb & 7) << 4));
    }
  }
  const char* ldsc = (const char*)lds;
  const int nkt = K >> 6;
  for (int kt = 0; kt < nkt; ++kt) {
    const char* gb = gsrc + (size_t)kt * 128;
#pragma unroll
    for (int r = 0; r < 8; ++r) {
      gload16(gb + (size_t)(r * 8 + lrow) * Kb + lcol, ltile + r * 512);
    }
    __syncthreads();
#pragma unroll
    for (int kk = 0; kk < 2; ++kk) {
      bf16x8 af[4], bfr[4];
#pragma unroll
      for (int i = 0; i < 4; ++i) {
        af[i]  = *(const bf16x8*)(ldsc + offA[i][kk]);
        bfr[i] = *(const bf16x8*)(ldsc + 16384 + offB[i][kk]);
      }
#pragma unroll
      for (int i = 0; i < 4; ++i)
#pragma unroll
        for (int j = 0; j < 4; ++j)
          acc[i][j] = __builtin_amdgcn_mfma_f32_16x16x32_bf16(af[i], bfr[j], acc[i][j], 0, 0, 0);
    }
    __syncthreads();
  }
  const int mirror = (blockIdx.y > blockIdx.x);
#pragma unroll
  for (int j = 0; j < 4; ++j) {
    int n = n0 + wn + j * 16 + (lane & 15);
#pragma unroll
    for (int i = 0; i < 4; ++i) {
      int mb = m0 + wm + i * 16 + ((lane >> 4) << 2);
      f32x4 a = acc[i][j];
#pragma unroll
      for (int r = 0; r < 4; ++r) {
        uint16_t hb = f2bf(a[r]);
        C[(size_t)(mb + r) * N + n] = hb;
        if (mirror) C[(size_t)n * N + (mb + r)] = hb;
      }
    }
  }
}

// ---------------------------------------------------------------------------
// v1: v = W^T u0 per layer — wave per row of Wt (bf16 swizzled), fp32 accum
// ---------------------------------------------------------------------------
__global__ __launch_bounds__(256) void v1_kernel(const uint16_t* __restrict__ Wt,
                                                 const float* u00, const float* u01,
                                                 const float* u02,
                                                 float* __restrict__ vout) {
  int gw = (blockIdx.x * 256 + threadIdx.x) >> 6;  // 0..5119
  int lane = threadIdx.x & 63;
  int layer = gw < 2048 ? 0 : (gw < 4096 ? 1 : 2);
  int j = gw - (layer == 0 ? 0 : (layer == 1 ? 2048 : 4096));
  int ni = layer == 0 ? 1024 : 2048;
  const uint16_t* row = Wt + (layer == 0 ? 0 : (layer == 1 ? 2097152 : 6291456)) + (size_t)j * ni;
  const float* u0 = layer == 0 ? u00 : (layer == 1 ? u01 : u02);
  int nc = ni >> 3;
  float part = 0.f;
  for (int c = lane; c < nc; c += 64) {
    int bo = (c * 16) ^ ((j & 7) << 4);
    short8 v = *(const short8*)((const char*)row + bo);
    const float4* up = (const float4*)(u0 + c * 8);
    float4 a = up[0], b = up[1];
    float us[8] = {a.x, a.y, a.z, a.w, b.x, b.y, b.z, b.w};
#pragma unroll
    for (int e = 0; e < 8; ++e) part += bf2f((uint16_t)((short*)&v)[e]) * us[e];
  }
  for (int o = 32; o; o >>= 1) part += __shfl_xor(part, o, 64);
  if (lane == 0) vout[layer * 2048 + j] = part;
}

// ---------------------------------------------------------------------------
// bmv: vout = B vin for all 3 layers (wave per row, bf16 B, fp32 accum)
// ---------------------------------------------------------------------------
__global__ __launch_bounds__(256) void bmv_kernel(const uint16_t* __restrict__ Bm,
                                                  const float* __restrict__ vin,
                                                  float* __restrict__ vout) {
  int gw = (blockIdx.x * 256 + threadIdx.x) >> 6;  // 0..5119
  int lane = threadIdx.x & 63;
  int layer = gw < 2048 ? 0 : (gw < 4096 ? 1 : 2);
  int r = gw - (layer == 0 ? 0 : (layer == 1 ? 2048 : 4096));
  int n = layer == 2 ? 1024 : 2048;
  const uint16_t* row = Bm + (layer == 0 ? 0 : (layer == 1 ? 4194304 : 8388608)) + (size_t)r * n;
  const float* v = vin + layer * 2048;
  float part = 0.f;
  for (int c = lane * 8; c < n; c += 512) {
    short8 w8 = *(const short8*)(row + c);
    const float4* vp = (const float4*)(v + c);
    float4 a = vp[0], b = vp[1];
    float vs[8] = {a.x, a.y, a.z, a.w, b.x, b.y, b.z, b.w};
#pragma unroll
    for (int e = 0; e < 8; ++e) part += bf2f((uint16_t)((short*)&w8)[e]) * vs[e];
  }
  for (int o = 32; o; o >>= 1) part += __shfl_xor(part, o, 64);
  if (lane == 0) vout[layer * 2048 + r] = part;
}

// ---------------------------------------------------------------------------
// dual GEMM: R3/R9's proven structure (best measured: 235us, absmax 1.0,
// conflicts 0) + T1 bijective XCD swizzle.
// 4 waves, 128x128 tile, BK=64, single 64KB buffer, 2 barriers per K-tile.
// acc_mu = A@B, acc_sd = A2@B2; epilogue fuses sqrt/eps/bias/relu.
// ---------------------------------------------------------------------------
__global__ __launch_bounds__(256, 2) void gemm_dual_kernel(
    const uint16_t* __restrict__ Ab, const uint16_t* __restrict__ A2b,
    const uint16_t* __restrict__ Bb, const uint16_t* __restrict__ B2b,
    const float* __restrict__ eps, const float* __restrict__ bias,
    uint16_t* __restrict__ Oh, uint16_t* __restrict__ Oh2,
    float* __restrict__ Oy, int K, int N, int last, int nwgx) {
  __shared__ uint16_t lds[32768];  // 64KB: A | A2 | B | B2 tiles of [128][64]
  const int t = threadIdx.x;
  const int w = t >> 6, lane = t & 63;

  // T1: bijective XCD swizzle (grid always % 8 == 0 here)
  const int nwg = gridDim.x;
  const int cpx = nwg >> 3;
  const int bid = blockIdx.x;
  const int logical = (bid & 7) * cpx + (bid >> 3);
  const int bx = logical % nwgx, by = logical / nwgx;

  const int m0 = by * 128, n0 = bx * 128;
  const int wm = (w >> 1) * 64, wn = (w & 1) * 64;
  const size_t Kb = (size_t)K * 2;

  f32x4 zero = {0.f, 0.f, 0.f, 0.f};
  f32x4 accm[4][4], accs[4][4];
#pragma unroll
  for (int i = 0; i < 4; ++i)
#pragma unroll
    for (int j = 0; j < 4; ++j) { accm[i][j] = zero; accs[i][j] = zero; }

  const uint16_t* mats[4] = {Ab, A2b, Bb, B2b};
  const int rb = (w < 2) ? m0 : n0;
  const char* gsrc = (const char*)mats[w] + (size_t)rb * Kb;
  const int lrow = lane >> 3;
  const int lcol = (lane & 7) * 16;
  uint16_t* ltile = lds + w * 8192;

  int offA[4][2], offB[4][2];
#pragma unroll
  for (int i = 0; i < 4; ++i) {
    int rowa = wm + i * 16 + (lane & 15);
    int rowb = wn + i * 16 + (lane & 15);
    int kp = (lane >> 4) << 4;
#pragma unroll
    for (int kk = 0; kk < 2; ++kk) {
      offA[i][kk] = (rowa << 7) + (((kk << 6) + kp) ^ ((rowa & 7) << 4));
      offB[i][kk] = (rowb << 7) + (((kk << 6) + kp) ^ ((rowb & 7) << 4));
    }
  }
  const char* ldsc = (const char*)lds;
  const int nkt = K >> 6;
  for (int kt = 0; kt < nkt; ++kt) {
    const char* gb = gsrc + (size_t)kt * 128;
#pragma unroll
    for (int r = 0; r < 16; ++r) {
      const char* src = gb + (size_t)(r * 8 + lrow) * Kb + lcol;
      gload16(src, ltile + r * 512);
    }
    __syncthreads();
#pragma unroll
    for (int kk = 0; kk < 2; ++kk) {
      bf16x8 af[4], a2f[4], bfr[4], b2f[4];
#pragma unroll
      for (int i = 0; i < 4; ++i) {
        af[i]  = *(const bf16x8*)(ldsc + offA[i][kk]);
        a2f[i] = *(const bf16x8*)(ldsc + 16384 + offA[i][kk]);
        bfr[i] = *(const bf16x8*)(ldsc + 32768 + offB[i][kk]);
        b2f[i] = *(const bf16x8*)(ldsc + 49152 + offB[i][kk]);
      }
#pragma unroll
      for (int i = 0; i < 4; ++i)
#pragma unroll
        for (int j = 0; j < 4; ++j) {
          accm[i][j] = __builtin_amdgcn_mfma_f32_16x16x32_bf16(af[i], bfr[j], accm[i][j], 0, 0, 0);
          accs[i][j] = __builtin_amdgcn_mfma_f32_16x16x32_bf16(a2f[i], b2f[j], accs[i][j], 0, 0, 0);
        }
    }
    __syncthreads();
  }
  // epilogue
  const int nstrb = N * 2;
#pragma unroll
  for (int j = 0; j < 4; ++j) {
    int n = n0 + wn + j * 16 + (lane & 15);
    float bn = bias[n];
#pragma unroll
    for (int i = 0; i < 4; ++i) {
      int mb = m0 + wm + i * 16 + ((lane >> 4) << 2);
      f32x4 am = accm[i][j], as = accs[i][j];
#pragma unroll
      for (int r = 0; r < 4; ++r) {
        int m = mb + r;
        float sd = sqrtf(fmaxf(as[r], 0.f));
        float val = am[r] + sd * eps[(size_t)m * N + n] + bn;
        if (last) {
          Oy[(size_t)m * N + n] = val;
        } else {
          float h = fmaxf(val, 0.f);
          size_t ob = (size_t)m * nstrb + ((n * 2) ^ ((m & 7) << 4));
          *(uint16_t*)((char*)Oh + ob) = f2bf(h);
          *(uint16_t*)((char*)Oh2 + ob) = f2bf(h * h);
        }
      }
    }
  }
}

// ---------------------------------------------------------------------------
// finalize: reduce sim partials; tkld, tlip.
// sigma = sqrt(dot(v10,Bv10)/dot(v10,v10))
// ---------------------------------------------------------------------------
__device__ __forceinline__ float block_red(float v, int is_max, float* red) {
  int t = threadIdx.x;
  red[t] = v;
  __syncthreads();
  for (int o = 128; o >= 1; o >>= 1) {
    if (t < o) red[t] = is_max ? fmaxf(red[t], red[t + o]) : (red[t] + red[t + o]);
    __syncthreads();
  }
  float r = red[0];
  __syncthreads();
  return r;
}

__global__ __launch_bounds__(256) void finalize_kernel(const float* __restrict__ acc,
                                                       const float* __restrict__ v10,
                                                       const float* __restrict__ wv,
                                                       const float* __restrict__ partial,
                                                       float* __restrict__ out2) {
  __shared__ float red[256];
  __shared__ float smax[30];
  int t = threadIdx.x;
  int w = t >> 6, lane = t & 63;
  for (int sl = w; sl < 30; sl += 4) {
    float m = 0.f;
    for (int b = lane; b < 2048; b += 64) m = fmaxf(m, partial[sl * 2048 + b]);
    for (int o = 32; o; o >>= 1) m = fmaxf(m, __shfl_xor(m, o, 64));
    if (lane == 0) smax[sl] = m;
  }
  __syncthreads();
  float tlip = 0.f;
  for (int layer = 0; layer < 3; ++layer) {
    int ni = layer == 0 ? 1024 : 2048;
    int no = layer == 2 ? 1024 : 2048;
    float mr = 0.f, mc = 0.f, s2n = 0.f, s2d = 0.f;
    for (int i = t; i < ni; i += 256) mr = fmaxf(mr, acc[64 + layer * 2048 + i]);
    for (int j = t; j < no; j += 256) mc = fmaxf(mc, acc[6208 + layer * 2048 + j]);
    for (int j = t; j < no; j += 256) {
      float v = v10[layer * 2048 + j], wv_ = wv[layer * 2048 + j];
      s2n += v * wv_;
      s2d += v * v;
    }
    mr = block_red(mr, 1, red);
    mc = block_red(mc, 1, red);
    s2n = block_red(s2n, 0, red);
    s2d = block_red(s2d, 0, red);
    if (t == 0) {
      float sm = 0.f;
      for (int s = 0; s < 10; ++s) sm += smax[layer * 10 + s];
      sm *= 0.1f;
      float sigma = sqrtf(s2n / s2d);
      float res = sqrtf(mr) + sqrtf(mc);
      float l = res + sm + sigma;
      tlip += l * l;
    }
  }
  if (t == 0) {
    out2[0] = acc[0];
    out2[1] = tlip;
  }
}

// ---------------------------------------------------------------------------
extern "C" void kernel_launch(void* const* d_in, const int* in_sizes, int n_in,
                              void* d_out, int out_size, void* d_ws, size_t ws_size,
                              hipStream_t stream) {
  (void)in_sizes; (void)n_in; (void)out_size; (void)ws_size;
  const float* x = (const float*)d_in[0];
  const float* Wmu[3] = {(const float*)d_in[1], (const float*)d_in[9],  (const float*)d_in[17]};
  const float* Wp[3]  = {(const float*)d_in[2], (const float*)d_in[10], (const float*)d_in[18]};
  const float* bmu[3] = {(const float*)d_in[3], (const float*)d_in[11], (const float*)d_in[19]};
  const float* bp[3]  = {(const float*)d_in[4], (const float*)d_in[12], (const float*)d_in[20]};
  const float* epsw[3]= {(const float*)d_in[5], (const float*)d_in[13], (const float*)d_in[21]};
  const float* epsb[3]= {(const float*)d_in[6], (const float*)d_in[14], (const float*)d_in[22]};
  const float* u0[3]  = {(const float*)d_in[7], (const float*)d_in[15], (const float*)d_in[23]};
  const float* sim[3] = {(const float*)d_in[8], (const float*)d_in[16], (const float*)d_in[24]};

  char* ws = (char*)d_ws;
  uint16_t* A0h  = (uint16_t*)(ws);
  uint16_t* A0h2 = (uint16_t*)(ws + 33554432);
  uint16_t* A1h  = (uint16_t*)(ws + 67108864);
  uint16_t* A1h2 = (uint16_t*)(ws + 100663296);
  uint16_t* Bmat = (uint16_t*)(ws + 67108864);  // bf16, aliases A1h: dead before gemm1
  uint16_t* Sgbf = (uint16_t*)(ws + 104857600); // aliases A1h2 tail: dead before gemm1
  uint16_t* Wt   = (uint16_t*)(ws + 134217728);
  uint16_t* St2  = (uint16_t*)(ws + 150994944);
  float* bias    = (float*)(ws + 167772160);
  float* pbuf0   = (float*)(ws + 167796736);
  float* pbuf1   = (float*)(ws + 167821312);
  float* acc     = (float*)(ws + 167845888);
  float* partial = (float*)(ws + 167895296);    // 30*2048 floats
  // acc layout: [0] kld | [64..6207] row2 | [6208..12351] col2

  hipMemsetAsync(ws + 167845888, 0, 49408, stream);

  prep_w_kernel<<<dim3(32, 32, 3), 256, 0, stream>>>(
      Wmu[0], Wp[0], Wmu[1], Wp[1], Wmu[2], Wp[2], Wt, St2, Sgbf, acc + 64, acc + 6208, acc);
  prep_x_kernel<<<4096, 256, 0, stream>>>(x, A0h, A0h2);
  prep_bias_kernel<<<20, 256, 0, stream>>>(
      bmu[0], bp[0], epsb[0], bmu[1], bp[1], epsb[1], bmu[2], bp[2], epsb[2], bias, acc);
  sim_max_kernel<<<2048, 256, 0, stream>>>(sim[0], sim[1], sim[2], Sgbf, partial);

  // B = W^T W per layer (symmetric, bf16 out), one launch
  gemm_nt_kernel<<<dim3(16, 16, 3), 256, 0, stream>>>(Wt, Bmat);

  // v1 = W^T u0 ; then v_{k+1} = B v_k ; v10 in pbuf1, w = B v10 in pbuf0
  v1_kernel<<<1280, 256, 0, stream>>>(Wt, u0[0], u0[1], u0[2], pbuf0);
  for (int it = 0; it < 10; ++it) {
    const float* vin = (it & 1) ? pbuf1 : pbuf0;
    float* vout = (it & 1) ? pbuf0 : pbuf1;
    bmv_kernel<<<1280, 256, 0, stream>>>(Bmat, vin, vout);
  }

  float* y = (float*)d_out;
  gemm_dual_kernel<<<1024, 256, 0, stream>>>(
      A0h, A0h2, Wt, St2, epsw[0], bias, A1h, A1h2, nullptr, 1024, 2048, 0, 16);
  gemm_dual_kernel<<<1024, 256, 0, stream>>>(
      A1h, A1h2, Wt + 2097152, St2 + 2097152, epsw[1], bias + 2048, A0h, A0h2, nullptr, 2048, 2048, 0, 16);
  gemm_dual_kernel<<<512, 256, 0, stream>>>(
      A0h, A0h2, Wt + 6291456, St2 + 6291456, epsw[2], bias + 4096, nullptr, nullptr, y, 2048, 1024, 1, 8);

  finalize_kernel<<<1, 256, 0, stream>>>(acc, pbuf1, pbuf0, partial, y + 8388608);
}

// Round 12
// 744.414 us; speedup vs baseline: 1.2799x; 1.1435x over previous
//
#include <hip/hip_runtime.h>
#include <stdint.h>

typedef __attribute__((ext_vector_type(8))) __bf16 bf16x8;
typedef __attribute__((ext_vector_type(8))) short short8;
typedef __attribute__((ext_vector_type(4))) float f32x4;
typedef long long i64;

#define LOG_P01 (-2.302585093f)   // log(0.1)

__device__ __forceinline__ uint16_t f2bf(float f) {
  union { float f; uint32_t u; } v; v.f = f;
  uint32_t r = (v.u + 0x7fffu + ((v.u >> 16) & 1u)) >> 16;
  return (uint16_t)r;
}
__device__ __forceinline__ float bf2f(uint16_t u) {
  union { uint32_t u; float f; } v; v.u = ((uint32_t)u) << 16;
  return v.f;
}
__device__ __forceinline__ uint8_t f2fp8(float f) {
  return (uint8_t)(__builtin_amdgcn_cvt_pk_fp8_f32(f, f, 0, false) & 0xff);
}
__device__ __forceinline__ float softplus1(float x) { return 1e-6f + log1pf(expf(x)); }

__device__ __forceinline__ void gload16(const void* g, void* l) {
  __builtin_amdgcn_global_load_lds(
      (__attribute__((address_space(1))) void*)(g),
      (__attribute__((address_space(3))) void*)(l), 16, 0, 0);
}

// ---------------------------------------------------------------------------
// prep_w: sigma = 1e-6+softplus(W_p);
//  - Wt bf16 transposed swizzled (for gemm_nt, v1)
//  - Wf fp8 + Sf2 fp8 (= sigma^2 * 256) transposed swizzled (for duals)
//  - Sg bf16 plain (sim_max); row/col norm^2 partials; KLD partial
// fp8 global layout: byte = j*ni + (k ^ ((j&7)<<4))
// ---------------------------------------------------------------------------
__global__ __launch_bounds__(256) void prep_w_kernel(
    const float* __restrict__ Wmu0, const float* __restrict__ Wp0,
    const float* __restrict__ Wmu1, const float* __restrict__ Wp1,
    const float* __restrict__ Wmu2, const float* __restrict__ Wp2,
    uint16_t* __restrict__ Wt, uint8_t* __restrict__ Wf, uint8_t* __restrict__ Sf2,
    uint16_t* __restrict__ Sg,
    float* __restrict__ row2, float* __restrict__ col2, float* __restrict__ kld) {
  const int layer = blockIdx.z;
  const int ni = (layer == 0) ? 1024 : 2048;
  const int no = (layer == 2) ? 1024 : 2048;
  if ((int)blockIdx.x >= (ni >> 6) || (int)blockIdx.y >= (no >> 6)) return;
  const float* Wmu = layer == 0 ? Wmu0 : (layer == 1 ? Wmu1 : Wmu2);
  const float* Wp  = layer == 0 ? Wp0  : (layer == 1 ? Wp1  : Wp2);
  const size_t wofs = layer == 0 ? 0 : (layer == 1 ? 2097152 : 6291456);
  uint16_t* wt = Wt + wofs;
  uint8_t* wf = Wf + wofs;
  uint8_t* sf = Sf2 + wofs;
  uint16_t* sgb = Sg + wofs;
  float* r2 = row2 + layer * 2048;
  float* c2 = col2 + layer * 2048;

  __shared__ uint16_t lmu[64][72];
  __shared__ __align__(16) uint8_t l8mu[64][80];
  __shared__ __align__(16) uint8_t l8s2[64][80];
  __shared__ float red[256];

  const int t = threadIdx.x;
  const int i0 = blockIdx.x * 64, j0 = blockIdx.y * 64;
  const int w = t >> 6, lane = t & 63;
  float colpart = 0.f, kpart = 0.f;
#pragma unroll
  for (int rep = 0; rep < 16; ++rep) {
    int il = rep * 4 + w;
    int jl = lane;
    size_t gi = (size_t)(i0 + il) * no + (j0 + jl);
    float mu = Wmu[gi], p = Wp[gi];
    float sg = softplus1(p);
    float s2 = sg * sg;
    kpart += 2.f * (LOG_P01 - logf(sg)) - 1.f + 100.f * s2 + 100.f * mu * mu;
    float rs = s2;
    for (int o = 32; o; o >>= 1) rs += __shfl_xor(rs, o, 64);
    if (lane == 0) atomicAdd(&r2[i0 + il], rs);
    colpart += s2;
    sgb[gi] = f2bf(sg);
    lmu[jl][il] = f2bf(mu);
    l8mu[jl][il] = f2fp8(mu);
    l8s2[jl][il] = f2fp8(s2 * 256.f);
  }
  red[t] = colpart;
  __syncthreads();
  if (t < 64) {
    float cs = red[t] + red[64 + t] + red[128 + t] + red[192 + t];
    atomicAdd(&c2[j0 + t], cs);
  }
  // bf16 Wt write-out (16B = 8 elems per chunk)
  const int Kb = ni * 2;
#pragma unroll
  for (int cc = 0; cc < 2; ++cc) {
    int c = cc * 256 + t;
    int nl = c >> 3, kc = c & 7;
    short8 vmu = *(const short8*)((const char*)&lmu[0][0] + nl * 144 + kc * 16);
    size_t db = (size_t)(j0 + nl) * Kb + (((i0 * 2 + kc * 16)) ^ ((nl & 7) << 4));
    *(short8*)((char*)wt + db) = vmu;
  }
  // fp8 write-out (16B = 16 elems per chunk; 64 rows x 4 chunks = 256 threads)
  {
    int nl = t >> 2, kc = t & 3;
    uint4 vm = *(const uint4*)&l8mu[nl][kc * 16];
    uint4 vs = *(const uint4*)&l8s2[nl][kc * 16];
    size_t db = (size_t)(j0 + nl) * ni + (size_t)(((i0 + kc * 16)) ^ ((nl & 7) << 4));
    *(uint4*)(wf + db) = vm;
    *(uint4*)(sf + db) = vs;
  }
  __syncthreads();
  red[t] = kpart;
  __syncthreads();
  for (int o = 128; o >= 1; o >>= 1) {
    if (t < o) red[t] += red[t + o];
    __syncthreads();
  }
  if (t == 0) atomicAdd(kld, 0.5f * red[0]);
}

// ---------------------------------------------------------------------------
// prep_x: fp8(x), fp8(x*x) into swizzled [8192][1024B] layout
// ---------------------------------------------------------------------------
__global__ __launch_bounds__(256) void prep_x_kernel(const float* __restrict__ x,
                                                     uint8_t* __restrict__ Af,
                                                     uint8_t* __restrict__ Af2) {
  size_t c = (size_t)blockIdx.x * 256 + threadIdx.x;  // 8-elem chunk
  size_t gidx = c * 8;
  if (gidx >= (size_t)8192 * 1024) return;
  int m = (int)(gidx >> 10);
  int k0 = (int)(gidx & 1023);
  const float4* xp = (const float4*)(x + gidx);
  float4 a = xp[0], b = xp[1];
  int lo = __builtin_amdgcn_cvt_pk_fp8_f32(a.x, a.y, 0, false);
  lo = __builtin_amdgcn_cvt_pk_fp8_f32(a.z, a.w, lo, true);
  int hi = __builtin_amdgcn_cvt_pk_fp8_f32(b.x, b.y, 0, false);
  hi = __builtin_amdgcn_cvt_pk_fp8_f32(b.z, b.w, hi, true);
  int slo = __builtin_amdgcn_cvt_pk_fp8_f32(a.x * a.x, a.y * a.y, 0, false);
  slo = __builtin_amdgcn_cvt_pk_fp8_f32(a.z * a.z, a.w * a.w, slo, true);
  int shi = __builtin_amdgcn_cvt_pk_fp8_f32(b.x * b.x, b.y * b.y, 0, false);
  shi = __builtin_amdgcn_cvt_pk_fp8_f32(b.z * b.z, b.w * b.w, shi, true);
  size_t ob = (size_t)m * 1024 + (size_t)(k0 ^ ((m & 7) << 4));
  *(uint2*)(Af + ob) = make_uint2((uint32_t)lo, (uint32_t)hi);
  *(uint2*)(Af2 + ob) = make_uint2((uint32_t)slo, (uint32_t)shi);
}

// ---------------------------------------------------------------------------
// prep_bias: bias[n] = b_mu + softplus(b_p)*eps_b ; bias KLD
// ---------------------------------------------------------------------------
__global__ __launch_bounds__(256) void prep_bias_kernel(
    const float* bmu0, const float* bp0, const float* eb0,
    const float* bmu1, const float* bp1, const float* eb1,
    const float* bmu2, const float* bp2, const float* eb2,
    float* __restrict__ bias, float* __restrict__ kld) {
  int t = blockIdx.x * 256 + threadIdx.x;
  float kpart = 0.f;
  if (t < 5120) {
    int layer = t < 2048 ? 0 : (t < 4096 ? 1 : 2);
    int n = t - (layer == 0 ? 0 : (layer == 1 ? 2048 : 4096));
    const float* bmu = layer == 0 ? bmu0 : (layer == 1 ? bmu1 : bmu2);
    const float* bp  = layer == 0 ? bp0  : (layer == 1 ? bp1  : bp2);
    const float* eb  = layer == 0 ? eb0  : (layer == 1 ? eb1  : eb2);
    float mu = bmu[n], p = bp[n], e = eb[n];
    float sg = softplus1(p);
    bias[layer * 2048 + n] = mu + sg * e;
    kpart = 0.5f * (2.f * (LOG_P01 - logf(sg)) - 1.f + 100.f * sg * sg + 100.f * mu * mu);
  }
  for (int o = 32; o; o >>= 1) kpart += __shfl_xor(kpart, o, 64);
  if ((threadIdx.x & 63) == 0) atomicAdd(kld, kpart);
}

// ---------------------------------------------------------------------------
// sim_max: single linear grid-stride pass over concatenated sim (320MB).
// ---------------------------------------------------------------------------
__global__ __launch_bounds__(256) void sim_max_kernel(
    const float* __restrict__ s0, const float* __restrict__ s1,
    const float* __restrict__ s2, const uint16_t* __restrict__ Sg,
    float* __restrict__ partial) {
  __shared__ int lmax[30];
  if (threadIdx.x < 30) lmax[threadIdx.x] = 0;
  __syncthreads();
  const size_t stride = (size_t)gridDim.x * 256;
  for (size_t c = (size_t)blockIdx.x * 256 + threadIdx.x; c < 20971520; c += stride) {
    const float* sp; size_t within; const uint16_t* sgp; int slot_base, shift;
    if (c < 5242880)       { sp = s0; within = c;            sgp = Sg;           slot_base = 0;  shift = 19; }
    else if (c < 15728640) { sp = s1; within = c - 5242880;  sgp = Sg + 2097152; slot_base = 10; shift = 20; }
    else                   { sp = s2; within = c - 15728640; sgp = Sg + 6291456; slot_base = 20; shift = 19; }
    int s = (int)(within >> shift);
    size_t idx = within - ((size_t)s << shift);
    float4 v = ((const float4*)sp)[within];
    ushort4 sv = *(const ushort4*)(sgp + idx * 4);
    float m = fmaxf(fmaxf(v.x * bf2f(sv.x), v.y * bf2f(sv.y)),
                    fmaxf(v.z * bf2f(sv.z), v.w * bf2f(sv.w)));
    for (int o = 32; o; o >>= 1) m = fmaxf(m, __shfl_xor(m, o, 64));
    if ((threadIdx.x & 63) == 0)
      atomicMax(&lmax[slot_base + s], __float_as_int(fmaxf(m, 0.f)));
  }
  __syncthreads();
  if (threadIdx.x < 30)
    partial[threadIdx.x * 2048 + blockIdx.x] = __int_as_float(lmax[threadIdx.x]);
}

// ---------------------------------------------------------------------------
// gemm_nt (3 layers, SYMMETRIC): C = R @ R^T, bf16 out (feeds bmv only).
// ---------------------------------------------------------------------------
__global__ __launch_bounds__(256, 2) void gemm_nt_kernel(
    const uint16_t* __restrict__ Wt, uint16_t* __restrict__ Bmat) {
  const int layer = blockIdx.z;
  const int K = (layer == 0) ? 1024 : 2048;
  const int N = (layer == 2) ? 1024 : 2048;
  if ((int)blockIdx.x >= (N >> 7) || (int)blockIdx.y >= (N >> 7)) return;
  if (blockIdx.y < blockIdx.x) return;  // symmetric: keep by >= bx
  const uint16_t* R = Wt + (layer == 0 ? 0 : (layer == 1 ? 2097152 : 6291456));
  uint16_t* C = Bmat + (layer == 0 ? 0 : (layer == 1 ? 4194304 : 8388608));

  __shared__ uint16_t lds[16384];  // 32KB
  const int t = threadIdx.x;
  const int w = t >> 6, lane = t & 63;
  const int m0 = blockIdx.y * 128, n0 = blockIdx.x * 128;
  const int wm = (w >> 1) * 64, wn = (w & 1) * 64;
  const size_t Kb = (size_t)K * 2;

  f32x4 zero = {0.f, 0.f, 0.f, 0.f};
  f32x4 acc[4][4];
#pragma unroll
  for (int i = 0; i < 4; ++i)
#pragma unroll
    for (int j = 0; j < 4; ++j) acc[i][j] = zero;

  const int rb = ((w < 2) ? m0 : n0) + (w & 1) * 64;
  const char* gsrc = (const char*)R + (size_t)rb * Kb;
  uint16_t* ltile = lds + (w < 2 ? 0 : 8192) + (w & 1) * 4096;
  const int lrow = lane >> 3;
  const int lcol = (lane & 7) * 16;

  int offA[4][2], offB[4][2];
#pragma unroll
  for (int i = 0; i < 4; ++i) {
    int rowa = wm + i * 16 + (lane & 15);
    int rowb = wn + i * 16 + (lane & 15);
    int kp = (lane >> 4) << 4;
#pragma unroll
    for (int kk = 0; kk < 2; ++kk) {
      offA[i][kk] = (rowa << 7) + (((kk << 6) + kp) ^ ((rowa & 7) << 4));
      offB[i][kk] = (rowb << 7) + (((kk << 6) + kp) ^ ((rowb & 7) << 4));
    }
  }
  const char* ldsc = (const char*)lds;
  const int nkt = K >> 6;
  for (int kt = 0; kt < nkt; ++kt) {
    const char* gb = gsrc + (size_t)kt * 128;
#pragma unroll
    for (int r = 0; r < 8; ++r) {
      gload16(gb + (size_t)(r * 8 + lrow) * Kb + lcol, ltile + r * 512);
    }
    __syncthreads();
#pragma unroll
    for (int kk = 0; kk < 2; ++kk) {
      bf16x8 af[4], bfr[4];
#pragma unroll
      for (int i = 0; i < 4; ++i) {
        af[i]  = *(const bf16x8*)(ldsc + offA[i][kk]);
        bfr[i] = *(const bf16x8*)(ldsc + 16384 + offB[i][kk]);
      }
#pragma unroll
      for (int i = 0; i < 4; ++i)
#pragma unroll
        for (int j = 0; j < 4; ++j)
          acc[i][j] = __builtin_amdgcn_mfma_f32_16x16x32_bf16(af[i], bfr[j], acc[i][j], 0, 0, 0);
    }
    __syncthreads();
  }
  const int mirror = (blockIdx.y > blockIdx.x);
#pragma unroll
  for (int j = 0; j < 4; ++j) {
    int n = n0 + wn + j * 16 + (lane & 15);
#pragma unroll
    for (int i = 0; i < 4; ++i) {
      int mb = m0 + wm + i * 16 + ((lane >> 4) << 2);
      f32x4 a = acc[i][j];
#pragma unroll
      for (int r = 0; r < 4; ++r) {
        uint16_t hb = f2bf(a[r]);
        C[(size_t)(mb + r) * N + n] = hb;
        if (mirror) C[(size_t)n * N + (mb + r)] = hb;
      }
    }
  }
}

// ---------------------------------------------------------------------------
// v1: v = W^T u0 per layer — wave per row of Wt (bf16 swizzled), fp32 accum
// ---------------------------------------------------------------------------
__global__ __launch_bounds__(256) void v1_kernel(const uint16_t* __restrict__ Wt,
                                                 const float* u00, const float* u01,
                                                 const float* u02,
                                                 float* __restrict__ vout) {
  int gw = (blockIdx.x * 256 + threadIdx.x) >> 6;  // 0..5119
  int lane = threadIdx.x & 63;
  int layer = gw < 2048 ? 0 : (gw < 4096 ? 1 : 2);
  int j = gw - (layer == 0 ? 0 : (layer == 1 ? 2048 : 4096));
  int ni = layer == 0 ? 1024 : 2048;
  const uint16_t* row = Wt + (layer == 0 ? 0 : (layer == 1 ? 2097152 : 6291456)) + (size_t)j * ni;
  const float* u0 = layer == 0 ? u00 : (layer == 1 ? u01 : u02);
  int nc = ni >> 3;
  float part = 0.f;
  for (int c = lane; c < nc; c += 64) {
    int bo = (c * 16) ^ ((j & 7) << 4);
    short8 v = *(const short8*)((const char*)row + bo);
    const float4* up = (const float4*)(u0 + c * 8);
    float4 a = up[0], b = up[1];
    float us[8] = {a.x, a.y, a.z, a.w, b.x, b.y, b.z, b.w};
#pragma unroll
    for (int e = 0; e < 8; ++e) part += bf2f((uint16_t)((short*)&v)[e]) * us[e];
  }
  for (int o = 32; o; o >>= 1) part += __shfl_xor(part, o, 64);
  if (lane == 0) vout[layer * 2048 + j] = part;
}

// ---------------------------------------------------------------------------
// bmv: vout = B vin for all 3 layers (wave per row, bf16 B, fp32 accum)
// ---------------------------------------------------------------------------
__global__ __launch_bounds__(256) void bmv_kernel(const uint16_t* __restrict__ Bm,
                                                  const float* __restrict__ vin,
                                                  float* __restrict__ vout) {
  int gw = (blockIdx.x * 256 + threadIdx.x) >> 6;  // 0..5119
  int lane = threadIdx.x & 63;
  int layer = gw < 2048 ? 0 : (gw < 4096 ? 1 : 2);
  int r = gw - (layer == 0 ? 0 : (layer == 1 ? 2048 : 4096));
  int n = layer == 2 ? 1024 : 2048;
  const uint16_t* row = Bm + (layer == 0 ? 0 : (layer == 1 ? 4194304 : 8388608)) + (size_t)r * n;
  const float* v = vin + layer * 2048;
  float part = 0.f;
  for (int c = lane * 8; c < n; c += 512) {
    short8 w8 = *(const short8*)(row + c);
    const float4* vp = (const float4*)(v + c);
    float4 a = vp[0], b = vp[1];
    float vs[8] = {a.x, a.y, a.z, a.w, b.x, b.y, b.z, b.w};
#pragma unroll
    for (int e = 0; e < 8; ++e) part += bf2f((uint16_t)((short*)&w8)[e]) * vs[e];
  }
  for (int o = 32; o; o >>= 1) part += __shfl_xor(part, o, 64);
  if (lane == 0) vout[layer * 2048 + r] = part;
}

// ---------------------------------------------------------------------------
// dual GEMM, fp8-e4m3: R3's proven 2-barrier schedule, BK=128 elems.
// LDS: 4 mats x [128][128B] = 64KB, 2 blocks/CU. 128 MFMA per 2 barriers
// (2x bf16's density); staged bytes halved.
// Global fp8 layout: byte = row*K + (k ^ ((row&7)<<4)); staging source linear
// (the baked XOR IS the lds swizzle); ds_read_b64 applies granule^(row&7)
// -> 2-way bank access (free).
// accs scaling: B2 = 256*sigma^2; A2 = x^2 (L0, sdinv=1/16) or h^2/16
// (L1/L2, sdinv=1/4): sd = sqrt(accs)*sdinv.
// ---------------------------------------------------------------------------
__global__ __launch_bounds__(256, 2) void gemm_dual_kernel(
    const uint8_t* __restrict__ Ab, const uint8_t* __restrict__ A2b,
    const uint8_t* __restrict__ Bb, const uint8_t* __restrict__ B2b,
    const float* __restrict__ eps, const float* __restrict__ bias,
    uint8_t* __restrict__ Oh, uint8_t* __restrict__ Oh2,
    float* __restrict__ Oy, int K, int N, int last, float sdinv, int nwgx) {
  __shared__ uint8_t lds[65536];  // A | A2 | B | B2, each [128][128B]
  const int t = threadIdx.x;
  const int w = t >> 6, lane = t & 63;

  // T1: bijective XCD swizzle (grid always % 8 == 0 here)
  const int nwg = gridDim.x;
  const int cpx = nwg >> 3;
  const int bid = blockIdx.x;
  const int logical = (bid & 7) * cpx + (bid >> 3);
  const int bx = logical % nwgx, by = logical / nwgx;

  const int m0 = by * 128, n0 = bx * 128;
  const int wm = (w >> 1) * 64, wn = (w & 1) * 64;
  const size_t Kb = (size_t)K;  // bytes per row

  f32x4 zero = {0.f, 0.f, 0.f, 0.f};
  f32x4 accm[4][4], accs[4][4];
#pragma unroll
  for (int i = 0; i < 4; ++i)
#pragma unroll
    for (int j = 0; j < 4; ++j) { accm[i][j] = zero; accs[i][j] = zero; }

  // staging: wave w stages matrix w (A, A2, B, B2), 16KB per K-tile
  const uint8_t* mats[4] = {Ab, A2b, Bb, B2b};
  const int rb = (w < 2) ? m0 : n0;
  const char* gsrc = (const char*)mats[w] + (size_t)rb * Kb;
  const int lrow = lane >> 3;          // 8 rows per iteration
  const int lcol = (lane & 7) * 16;    // 128B per row
  uint8_t* ltile = lds + w * 16384;

  int rowA[4], rowB[4];
#pragma unroll
  for (int i = 0; i < 4; ++i) {
    rowA[i] = wm + i * 16 + (lane & 15);
    rowB[i] = wn + i * 16 + (lane & 15);
  }
  const int klo = (lane >> 4) << 3;  // 8-byte sub-chunk within K=32 step

  const char* ldsc = (const char*)lds;
  const int nkt = K >> 7;
  for (int kt = 0; kt < nkt; ++kt) {
    const char* gb = gsrc + (size_t)kt * 128;
#pragma unroll
    for (int r = 0; r < 16; ++r) {
      gload16(gb + (size_t)(r * 8 + lrow) * Kb + lcol, ltile + r * 1024 + lane * 16);
    }
    __syncthreads();
#pragma unroll
    for (int kk = 0; kk < 4; ++kk) {
      const int ko = kk * 32 + klo;
      i64 af[4], a2f[4], bfr[4], b2f[4];
#pragma unroll
      for (int i = 0; i < 4; ++i) {
        int oa = rowA[i] * 128 + (ko ^ ((rowA[i] & 7) << 4));
        int ob = rowB[i] * 128 + (ko ^ ((rowB[i] & 7) << 4));
        af[i]  = *(const i64*)(ldsc + oa);
        a2f[i] = *(const i64*)(ldsc + 16384 + oa);
        bfr[i] = *(const i64*)(ldsc + 32768 + ob);
        b2f[i] = *(const i64*)(ldsc + 49152 + ob);
      }
#pragma unroll
      for (int i = 0; i < 4; ++i)
#pragma unroll
        for (int j = 0; j < 4; ++j) {
          accm[i][j] = __builtin_amdgcn_mfma_f32_16x16x32_fp8_fp8(af[i], bfr[j], accm[i][j], 0, 0, 0);
          accs[i][j] = __builtin_amdgcn_mfma_f32_16x16x32_fp8_fp8(a2f[i], b2f[j], accs[i][j], 0, 0, 0);
        }
    }
    __syncthreads();
  }
  // epilogue
#pragma unroll
  for (int j = 0; j < 4; ++j) {
    int n = n0 + wn + j * 16 + (lane & 15);
    float bn = bias[n];
#pragma unroll
    for (int i = 0; i < 4; ++i) {
      int mb = m0 + wm + i * 16 + ((lane >> 4) << 2);
      f32x4 am = accm[i][j], as = accs[i][j];
#pragma unroll
      for (int r = 0; r < 4; ++r) {
        int m = mb + r;
        float sd = sqrtf(fmaxf(as[r], 0.f)) * sdinv;
        float val = am[r] + sd * eps[(size_t)m * N + n] + bn;
        if (last) {
          Oy[(size_t)m * N + n] = val;
        } else {
          float h = fmaxf(val, 0.f);
          size_t ob = (size_t)m * N + (size_t)(n ^ ((m & 7) << 4));
          Oh[ob] = f2fp8(h);
          Oh2[ob] = f2fp8(h * h * 0.0625f);
        }
      }
    }
  }
}

// ---------------------------------------------------------------------------
// finalize: reduce sim partials; tkld, tlip.
// sigma = sqrt(dot(v10,Bv10)/dot(v10,v10))
// ---------------------------------------------------------------------------
__device__ __forceinline__ float block_red(float v, int is_max, float* red) {
  int t = threadIdx.x;
  red[t] = v;
  __syncthreads();
  for (int o = 128; o >= 1; o >>= 1) {
    if (t < o) red[t] = is_max ? fmaxf(red[t], red[t + o]) : (red[t] + red[t + o]);
    __syncthreads();
  }
  float r = red[0];
  __syncthreads();
  return r;
}

__global__ __launch_bounds__(256) void finalize_kernel(const float* __restrict__ acc,
                                                       const float* __restrict__ v10,
                                                       const float* __restrict__ wv,
                                                       const float* __restrict__ partial,
                                                       float* __restrict__ out2) {
  __shared__ float red[256];
  __shared__ float smax[30];
  int t = threadIdx.x;
  int w = t >> 6, lane = t & 63;
  for (int sl = w; sl < 30; sl += 4) {
    float m = 0.f;
    for (int b = lane; b < 2048; b += 64) m = fmaxf(m, partial[sl * 2048 + b]);
    for (int o = 32; o; o >>= 1) m = fmaxf(m, __shfl_xor(m, o, 64));
    if (lane == 0) smax[sl] = m;
  }
  __syncthreads();
  float tlip = 0.f;
  for (int layer = 0; layer < 3; ++layer) {
    int ni = layer == 0 ? 1024 : 2048;
    int no = layer == 2 ? 1024 : 2048;
    float mr = 0.f, mc = 0.f, s2n = 0.f, s2d = 0.f;
    for (int i = t; i < ni; i += 256) mr = fmaxf(mr, acc[64 + layer * 2048 + i]);
    for (int j = t; j < no; j += 256) mc = fmaxf(mc, acc[6208 + layer * 2048 + j]);
    for (int j = t; j < no; j += 256) {
      float v = v10[layer * 2048 + j], wv_ = wv[layer * 2048 + j];
      s2n += v * wv_;
      s2d += v * v;
    }
    mr = block_red(mr, 1, red);
    mc = block_red(mc, 1, red);
    s2n = block_red(s2n, 0, red);
    s2d = block_red(s2d, 0, red);
    if (t == 0) {
      float sm = 0.f;
      for (int s = 0; s < 10; ++s) sm += smax[layer * 10 + s];
      sm *= 0.1f;
      float sigma = sqrtf(s2n / s2d);
      float res = sqrtf(mr) + sqrtf(mc);
      float l = res + sm + sigma;
      tlip += l * l;
    }
  }
  if (t == 0) {
    out2[0] = acc[0];
    out2[1] = tlip;
  }
}

// ---------------------------------------------------------------------------
extern "C" void kernel_launch(void* const* d_in, const int* in_sizes, int n_in,
                              void* d_out, int out_size, void* d_ws, size_t ws_size,
                              hipStream_t stream) {
  (void)in_sizes; (void)n_in; (void)out_size; (void)ws_size;
  const float* x = (const float*)d_in[0];
  const float* Wmu[3] = {(const float*)d_in[1], (const float*)d_in[9],  (const float*)d_in[17]};
  const float* Wp[3]  = {(const float*)d_in[2], (const float*)d_in[10], (const float*)d_in[18]};
  const float* bmu[3] = {(const float*)d_in[3], (const float*)d_in[11], (const float*)d_in[19]};
  const float* bp[3]  = {(const float*)d_in[4], (const float*)d_in[12], (const float*)d_in[20]};
  const float* epsw[3]= {(const float*)d_in[5], (const float*)d_in[13], (const float*)d_in[21]};
  const float* epsb[3]= {(const float*)d_in[6], (const float*)d_in[14], (const float*)d_in[22]};
  const float* u0[3]  = {(const float*)d_in[7], (const float*)d_in[15], (const float*)d_in[23]};
  const float* sim[3] = {(const float*)d_in[8], (const float*)d_in[16], (const float*)d_in[24]};

  char* ws = (char*)d_ws;
  uint8_t*  A0f  = (uint8_t*)(ws);                 // 8 MB  (x fp8)
  uint8_t*  A0f2 = (uint8_t*)(ws + 8388608);       // 8 MB  (x^2 fp8)
  uint8_t*  A1f  = (uint8_t*)(ws + 16777216);      // 16 MB (h1)
  uint8_t*  A1f2 = (uint8_t*)(ws + 33554432);      // 16 MB (h1^2/16)
  uint8_t*  A2f  = (uint8_t*)(ws + 50331648);      // 16 MB (h2)
  uint8_t*  A2f2 = (uint8_t*)(ws + 67108864);      // 16 MB (h2^2/16)
  uint8_t*  Wf   = (uint8_t*)(ws + 83886080);      // 8 MB  (W fp8)
  uint8_t*  Sf2  = (uint8_t*)(ws + 92274688);      // 8 MB  (256*sigma^2 fp8)
  uint16_t* Bmat = (uint16_t*)(ws + 100663296);    // ~19 MB bf16
  uint16_t* Sgbf = (uint16_t*)(ws + 119537664);    // 16 MB bf16 sigma
  uint16_t* Wt   = (uint16_t*)(ws + 136314880);    // 16 MB bf16 W^T
  float* bias    = (float*)(ws + 153092096);
  float* pbuf0   = (float*)(ws + 153116672);
  float* pbuf1   = (float*)(ws + 153141248);
  float* acc     = (float*)(ws + 153165824);       // [0] kld | [64..] row2 | [6208..] col2
  float* partial = (float*)(ws + 153215232);       // 30*2048 floats

  hipMemsetAsync(ws + 153165824, 0, 49408, stream);

  prep_w_kernel<<<dim3(32, 32, 3), 256, 0, stream>>>(
      Wmu[0], Wp[0], Wmu[1], Wp[1], Wmu[2], Wp[2], Wt, Wf, Sf2, Sgbf,
      acc + 64, acc + 6208, acc);
  prep_x_kernel<<<4096, 256, 0, stream>>>(x, A0f, A0f2);
  prep_bias_kernel<<<20, 256, 0, stream>>>(
      bmu[0], bp[0], epsb[0], bmu[1], bp[1], epsb[1], bmu[2], bp[2], epsb[2], bias, acc);
  sim_max_kernel<<<2048, 256, 0, stream>>>(sim[0], sim[1], sim[2], Sgbf, partial);

  // B = W^T W per layer (symmetric, bf16 out), one launch
  gemm_nt_kernel<<<dim3(16, 16, 3), 256, 0, stream>>>(Wt, Bmat);

  // v1 = W^T u0 ; then v_{k+1} = B v_k ; v10 in pbuf1, w = B v10 in pbuf0
  v1_kernel<<<1280, 256, 0, stream>>>(Wt, u0[0], u0[1], u0[2], pbuf0);
  for (int it = 0; it < 10; ++it) {
    const float* vin = (it & 1) ? pbuf1 : pbuf0;
    float* vout = (it & 1) ? pbuf0 : pbuf1;
    bmv_kernel<<<1280, 256, 0, stream>>>(Bmat, vin, vout);
  }

  float* y = (float*)d_out;
  gemm_dual_kernel<<<1024, 256, 0, stream>>>(
      A0f, A0f2, Wf, Sf2, epsw[0], bias, A1f, A1f2, nullptr,
      1024, 2048, 0, 0.0625f, 16);
  gemm_dual_kernel<<<1024, 256, 0, stream>>>(
      A1f, A1f2, Wf + 2097152, Sf2 + 2097152, epsw[1], bias + 2048, A2f, A2f2, nullptr,
      2048, 2048, 0, 0.25f, 16);
  gemm_dual_kernel<<<512, 256, 0, stream>>>(
      A2f, A2f2, Wf + 6291456, Sf2 + 6291456, epsw[2], bias + 4096, nullptr, nullptr, y,
      2048, 1024, 1, 0.25f, 8);

  finalize_kernel<<<1, 256, 0, stream>>>(acc, pbuf1, pbuf0, partial, y + 8388608);
}

// Round 13
// 727.956 us; speedup vs baseline: 1.3088x; 1.0226x over previous
//
#include <hip/hip_runtime.h>
#include <stdint.h>

typedef __attribute__((ext_vector_type(8))) __bf16 bf16x8;
typedef __attribute__((ext_vector_type(8))) short short8;
typedef __attribute__((ext_vector_type(4))) float f32x4;
typedef long long i64;

#define LOG_P01 (-2.302585093f)   // log(0.1)

__device__ __forceinline__ uint16_t f2bf(float f) {
  union { float f; uint32_t u; } v; v.f = f;
  uint32_t r = (v.u + 0x7fffu + ((v.u >> 16) & 1u)) >> 16;
  return (uint16_t)r;
}
__device__ __forceinline__ float bf2f(uint16_t u) {
  union { uint32_t u; float f; } v; v.u = ((uint32_t)u) << 16;
  return v.f;
}
__device__ __forceinline__ uint8_t f2fp8(float f) {
  return (uint8_t)(__builtin_amdgcn_cvt_pk_fp8_f32(f, f, 0, false) & 0xff);
}
__device__ __forceinline__ float softplus1(float x) { return 1e-6f + log1pf(expf(x)); }

__device__ __forceinline__ void gload16(const void* g, void* l) {
  __builtin_amdgcn_global_load_lds(
      (__attribute__((address_space(1))) void*)(g),
      (__attribute__((address_space(3))) void*)(l), 16, 0, 0);
}

// fp8 layout function: byte = k ^ ((row&7)<<4) ^ (((row>>3)&1)<<3)
// (involution per row; quarter-wave b64 reads cover all 32 banks once)

// ---------------------------------------------------------------------------
// prep_w: sigma = 1e-6+softplus(W_p);
//  - Wt bf16 transposed swizzled (for gemm_nt, v1)
//  - Wf fp8 + Sf2 fp8 (= sigma^2 * 256) transposed, fp8-layout
//  - Sg bf16 plain (sim_max); row/col norm^2 partials; KLD partial
// ---------------------------------------------------------------------------
__global__ __launch_bounds__(256) void prep_w_kernel(
    const float* __restrict__ Wmu0, const float* __restrict__ Wp0,
    const float* __restrict__ Wmu1, const float* __restrict__ Wp1,
    const float* __restrict__ Wmu2, const float* __restrict__ Wp2,
    uint16_t* __restrict__ Wt, uint8_t* __restrict__ Wf, uint8_t* __restrict__ Sf2,
    uint16_t* __restrict__ Sg,
    float* __restrict__ row2, float* __restrict__ col2, float* __restrict__ kld) {
  const int layer = blockIdx.z;
  const int ni = (layer == 0) ? 1024 : 2048;
  const int no = (layer == 2) ? 1024 : 2048;
  if ((int)blockIdx.x >= (ni >> 6) || (int)blockIdx.y >= (no >> 6)) return;
  const float* Wmu = layer == 0 ? Wmu0 : (layer == 1 ? Wmu1 : Wmu2);
  const float* Wp  = layer == 0 ? Wp0  : (layer == 1 ? Wp1  : Wp2);
  const size_t wofs = layer == 0 ? 0 : (layer == 1 ? 2097152 : 6291456);
  uint16_t* wt = Wt + wofs;
  uint8_t* wf = Wf + wofs;
  uint8_t* sf = Sf2 + wofs;
  uint16_t* sgb = Sg + wofs;
  float* r2 = row2 + layer * 2048;
  float* c2 = col2 + layer * 2048;

  __shared__ uint16_t lmu[64][72];
  __shared__ __align__(16) uint8_t l8mu[64][80];
  __shared__ __align__(16) uint8_t l8s2[64][80];
  __shared__ float red[256];

  const int t = threadIdx.x;
  const int i0 = blockIdx.x * 64, j0 = blockIdx.y * 64;
  const int w = t >> 6, lane = t & 63;
  float colpart = 0.f, kpart = 0.f;
#pragma unroll
  for (int rep = 0; rep < 16; ++rep) {
    int il = rep * 4 + w;
    int jl = lane;
    size_t gi = (size_t)(i0 + il) * no + (j0 + jl);
    float mu = Wmu[gi], p = Wp[gi];
    float sg = softplus1(p);
    float s2 = sg * sg;
    kpart += 2.f * (LOG_P01 - logf(sg)) - 1.f + 100.f * s2 + 100.f * mu * mu;
    float rs = s2;
    for (int o = 32; o; o >>= 1) rs += __shfl_xor(rs, o, 64);
    if (lane == 0) atomicAdd(&r2[i0 + il], rs);
    colpart += s2;
    sgb[gi] = f2bf(sg);
    lmu[jl][il] = f2bf(mu);
    l8mu[jl][il] = f2fp8(mu);
    l8s2[jl][il] = f2fp8(s2 * 256.f);
  }
  red[t] = colpart;
  __syncthreads();
  if (t < 64) {
    float cs = red[t] + red[64 + t] + red[128 + t] + red[192 + t];
    atomicAdd(&c2[j0 + t], cs);
  }
  // bf16 Wt write-out (16B = 8 elems per chunk)
  const int Kb = ni * 2;
#pragma unroll
  for (int cc = 0; cc < 2; ++cc) {
    int c = cc * 256 + t;
    int nl = c >> 3, kc = c & 7;
    short8 vmu = *(const short8*)((const char*)&lmu[0][0] + nl * 144 + kc * 16);
    size_t db = (size_t)(j0 + nl) * Kb + (((i0 * 2 + kc * 16)) ^ ((nl & 7) << 4));
    *(short8*)((char*)wt + db) = vmu;
  }
  // fp8 write-out (16B chunks; swap 8B halves when row bit3 set)
  {
    int nl = t >> 2, kc = t & 3;
    uint4 vm = *(const uint4*)&l8mu[nl][kc * 16];
    uint4 vs = *(const uint4*)&l8s2[nl][kc * 16];
    if ((nl >> 3) & 1) {
      vm = make_uint4(vm.z, vm.w, vm.x, vm.y);
      vs = make_uint4(vs.z, vs.w, vs.x, vs.y);
    }
    size_t db = (size_t)(j0 + nl) * ni + (size_t)(((i0 + kc * 16)) ^ ((nl & 7) << 4));
    *(uint4*)(wf + db) = vm;
    *(uint4*)(sf + db) = vs;
  }
  __syncthreads();
  red[t] = kpart;
  __syncthreads();
  for (int o = 128; o >= 1; o >>= 1) {
    if (t < o) red[t] += red[t + o];
    __syncthreads();
  }
  if (t == 0) atomicAdd(kld, 0.5f * red[0]);
}

// ---------------------------------------------------------------------------
// prep_x: fp8(x), fp8(x*x) into fp8-layout [8192][1024B]
// ---------------------------------------------------------------------------
__global__ __launch_bounds__(256) void prep_x_kernel(const float* __restrict__ x,
                                                     uint8_t* __restrict__ Af,
                                                     uint8_t* __restrict__ Af2) {
  size_t c = (size_t)blockIdx.x * 256 + threadIdx.x;  // 8-elem chunk
  size_t gidx = c * 8;
  if (gidx >= (size_t)8192 * 1024) return;
  int m = (int)(gidx >> 10);
  int k0 = (int)(gidx & 1023);
  const float4* xp = (const float4*)(x + gidx);
  float4 a = xp[0], b = xp[1];
  int lo = __builtin_amdgcn_cvt_pk_fp8_f32(a.x, a.y, 0, false);
  lo = __builtin_amdgcn_cvt_pk_fp8_f32(a.z, a.w, lo, true);
  int hi = __builtin_amdgcn_cvt_pk_fp8_f32(b.x, b.y, 0, false);
  hi = __builtin_amdgcn_cvt_pk_fp8_f32(b.z, b.w, hi, true);
  int slo = __builtin_amdgcn_cvt_pk_fp8_f32(a.x * a.x, a.y * a.y, 0, false);
  slo = __builtin_amdgcn_cvt_pk_fp8_f32(a.z * a.z, a.w * a.w, slo, true);
  int shi = __builtin_amdgcn_cvt_pk_fp8_f32(b.x * b.x, b.y * b.y, 0, false);
  shi = __builtin_amdgcn_cvt_pk_fp8_f32(b.z * b.z, b.w * b.w, shi, true);
  size_t ob = (size_t)m * 1024 +
              (size_t)((k0 ^ ((m & 7) << 4)) ^ (((m >> 3) & 1) << 3));
  *(uint2*)(Af + ob) = make_uint2((uint32_t)lo, (uint32_t)hi);
  *(uint2*)(Af2 + ob) = make_uint2((uint32_t)slo, (uint32_t)shi);
}

// ---------------------------------------------------------------------------
// prep_bias: bias[n] = b_mu + softplus(b_p)*eps_b ; bias KLD
// ---------------------------------------------------------------------------
__global__ __launch_bounds__(256) void prep_bias_kernel(
    const float* bmu0, const float* bp0, const float* eb0,
    const float* bmu1, const float* bp1, const float* eb1,
    const float* bmu2, const float* bp2, const float* eb2,
    float* __restrict__ bias, float* __restrict__ kld) {
  int t = blockIdx.x * 256 + threadIdx.x;
  float kpart = 0.f;
  if (t < 5120) {
    int layer = t < 2048 ? 0 : (t < 4096 ? 1 : 2);
    int n = t - (layer == 0 ? 0 : (layer == 1 ? 2048 : 4096));
    const float* bmu = layer == 0 ? bmu0 : (layer == 1 ? bmu1 : bmu2);
    const float* bp  = layer == 0 ? bp0  : (layer == 1 ? bp1  : bp2);
    const float* eb  = layer == 0 ? eb0  : (layer == 1 ? eb1  : eb2);
    float mu = bmu[n], p = bp[n], e = eb[n];
    float sg = softplus1(p);
    bias[layer * 2048 + n] = mu + sg * e;
    kpart = 0.5f * (2.f * (LOG_P01 - logf(sg)) - 1.f + 100.f * sg * sg + 100.f * mu * mu);
  }
  for (int o = 32; o; o >>= 1) kpart += __shfl_xor(kpart, o, 64);
  if ((threadIdx.x & 63) == 0) atomicAdd(kld, kpart);
}

// ---------------------------------------------------------------------------
// sim_max: single linear grid-stride pass over concatenated sim (320MB).
// ---------------------------------------------------------------------------
__global__ __launch_bounds__(256) void sim_max_kernel(
    const float* __restrict__ s0, const float* __restrict__ s1,
    const float* __restrict__ s2, const uint16_t* __restrict__ Sg,
    float* __restrict__ partial) {
  __shared__ int lmax[30];
  if (threadIdx.x < 30) lmax[threadIdx.x] = 0;
  __syncthreads();
  const size_t stride = (size_t)gridDim.x * 256;
  for (size_t c = (size_t)blockIdx.x * 256 + threadIdx.x; c < 20971520; c += stride) {
    const float* sp; size_t within; const uint16_t* sgp; int slot_base, shift;
    if (c < 5242880)       { sp = s0; within = c;            sgp = Sg;           slot_base = 0;  shift = 19; }
    else if (c < 15728640) { sp = s1; within = c - 5242880;  sgp = Sg + 2097152; slot_base = 10; shift = 20; }
    else                   { sp = s2; within = c - 15728640; sgp = Sg + 6291456; slot_base = 20; shift = 19; }
    int s = (int)(within >> shift);
    size_t idx = within - ((size_t)s << shift);
    float4 v = ((const float4*)sp)[within];
    ushort4 sv = *(const ushort4*)(sgp + idx * 4);
    float m = fmaxf(fmaxf(v.x * bf2f(sv.x), v.y * bf2f(sv.y)),
                    fmaxf(v.z * bf2f(sv.z), v.w * bf2f(sv.w)));
    for (int o = 32; o; o >>= 1) m = fmaxf(m, __shfl_xor(m, o, 64));
    if ((threadIdx.x & 63) == 0)
      atomicMax(&lmax[slot_base + s], __float_as_int(fmaxf(m, 0.f)));
  }
  __syncthreads();
  if (threadIdx.x < 30)
    partial[threadIdx.x * 2048 + blockIdx.x] = __int_as_float(lmax[threadIdx.x]);
}

// ---------------------------------------------------------------------------
// gemm_nt (3 layers, SYMMETRIC): C = R @ R^T, bf16 out (feeds bmv only).
// ---------------------------------------------------------------------------
__global__ __launch_bounds__(256, 2) void gemm_nt_kernel(
    const uint16_t* __restrict__ Wt, uint16_t* __restrict__ Bmat) {
  const int layer = blockIdx.z;
  const int K = (layer == 0) ? 1024 : 2048;
  const int N = (layer == 2) ? 1024 : 2048;
  if ((int)blockIdx.x >= (N >> 7) || (int)blockIdx.y >= (N >> 7)) return;
  if (blockIdx.y < blockIdx.x) return;  // symmetric: keep by >= bx
  const uint16_t* R = Wt + (layer == 0 ? 0 : (layer == 1 ? 2097152 : 6291456));
  uint16_t* C = Bmat + (layer == 0 ? 0 : (layer == 1 ? 4194304 : 8388608));

  __shared__ uint16_t lds[16384];  // 32KB
  const int t = threadIdx.x;
  const int w = t >> 6, lane = t & 63;
  const int m0 = blockIdx.y * 128, n0 = blockIdx.x * 128;
  const int wm = (w >> 1) * 64, wn = (w & 1) * 64;
  const size_t Kb = (size_t)K * 2;

  f32x4 zero = {0.f, 0.f, 0.f, 0.f};
  f32x4 acc[4][4];
#pragma unroll
  for (int i = 0; i < 4; ++i)
#pragma unroll
    for (int j = 0; j < 4; ++j) acc[i][j] = zero;

  const int rb = ((w < 2) ? m0 : n0) + (w & 1) * 64;
  const char* gsrc = (const char*)R + (size_t)rb * Kb;
  uint16_t* ltile = lds + (w < 2 ? 0 : 8192) + (w & 1) * 4096;
  const int lrow = lane >> 3;
  const int lcol = (lane & 7) * 16;

  int offA[4][2], offB[4][2];
#pragma unroll
  for (int i = 0; i < 4; ++i) {
    int rowa = wm + i * 16 + (lane & 15);
    int rowb = wn + i * 16 + (lane & 15);
    int kp = (lane >> 4) << 4;
#pragma unroll
    for (int kk = 0; kk < 2; ++kk) {
      offA[i][kk] = (rowa << 7) + (((kk << 6) + kp) ^ ((rowa & 7) << 4));
      offB[i][kk] = (rowb << 7) + (((kk << 6) + kp) ^ ((rowb & 7) << 4));
    }
  }
  const char* ldsc = (const char*)lds;
  const int nkt = K >> 6;
  for (int kt = 0; kt < nkt; ++kt) {
    const char* gb = gsrc + (size_t)kt * 128;
#pragma unroll
    for (int r = 0; r < 8; ++r) {
      gload16(gb + (size_t)(r * 8 + lrow) * Kb + lcol, ltile + r * 512);
    }
    __syncthreads();
#pragma unroll
    for (int kk = 0; kk < 2; ++kk) {
      bf16x8 af[4], bfr[4];
#pragma unroll
      for (int i = 0; i < 4; ++i) {
        af[i]  = *(const bf16x8*)(ldsc + offA[i][kk]);
        bfr[i] = *(const bf16x8*)(ldsc + 16384 + offB[i][kk]);
      }
#pragma unroll
      for (int i = 0; i < 4; ++i)
#pragma unroll
        for (int j = 0; j < 4; ++j)
          acc[i][j] = __builtin_amdgcn_mfma_f32_16x16x32_bf16(af[i], bfr[j], acc[i][j], 0, 0, 0);
    }
    __syncthreads();
  }
  const int mirror = (blockIdx.y > blockIdx.x);
#pragma unroll
  for (int j = 0; j < 4; ++j) {
    int n = n0 + wn + j * 16 + (lane & 15);
#pragma unroll
    for (int i = 0; i < 4; ++i) {
      int mb = m0 + wm + i * 16 + ((lane >> 4) << 2);
      f32x4 a = acc[i][j];
#pragma unroll
      for (int r = 0; r < 4; ++r) {
        uint16_t hb = f2bf(a[r]);
        C[(size_t)(mb + r) * N + n] = hb;
        if (mirror) C[(size_t)n * N + (mb + r)] = hb;
      }
    }
  }
}

// ---------------------------------------------------------------------------
// v1: v = W^T u0 per layer — wave per row of Wt (bf16 swizzled), fp32 accum
// ---------------------------------------------------------------------------
__global__ __launch_bounds__(256) void v1_kernel(const uint16_t* __restrict__ Wt,
                                                 const float* u00, const float* u01,
                                                 const float* u02,
                                                 float* __restrict__ vout) {
  int gw = (blockIdx.x * 256 + threadIdx.x) >> 6;  // 0..5119
  int lane = threadIdx.x & 63;
  int layer = gw < 2048 ? 0 : (gw < 4096 ? 1 : 2);
  int j = gw - (layer == 0 ? 0 : (layer == 1 ? 2048 : 4096));
  int ni = layer == 0 ? 1024 : 2048;
  const uint16_t* row = Wt + (layer == 0 ? 0 : (layer == 1 ? 2097152 : 6291456)) + (size_t)j * ni;
  const float* u0 = layer == 0 ? u00 : (layer == 1 ? u01 : u02);
  int nc = ni >> 3;
  float part = 0.f;
  for (int c = lane; c < nc; c += 64) {
    int bo = (c * 16) ^ ((j & 7) << 4);
    short8 v = *(const short8*)((const char*)row + bo);
    const float4* up = (const float4*)(u0 + c * 8);
    float4 a = up[0], b = up[1];
    float us[8] = {a.x, a.y, a.z, a.w, b.x, b.y, b.z, b.w};
#pragma unroll
    for (int e = 0; e < 8; ++e) part += bf2f((uint16_t)((short*)&v)[e]) * us[e];
  }
  for (int o = 32; o; o >>= 1) part += __shfl_xor(part, o, 64);
  if (lane == 0) vout[layer * 2048 + j] = part;
}

// ---------------------------------------------------------------------------
// bmv: vout = B vin for all 3 layers (wave per row, bf16 B, fp32 accum)
// ---------------------------------------------------------------------------
__global__ __launch_bounds__(256) void bmv_kernel(const uint16_t* __restrict__ Bm,
                                                  const float* __restrict__ vin,
                                                  float* __restrict__ vout) {
  int gw = (blockIdx.x * 256 + threadIdx.x) >> 6;  // 0..5119
  int lane = threadIdx.x & 63;
  int layer = gw < 2048 ? 0 : (gw < 4096 ? 1 : 2);
  int r = gw - (layer == 0 ? 0 : (layer == 1 ? 2048 : 4096));
  int n = layer == 2 ? 1024 : 2048;
  const uint16_t* row = Bm + (layer == 0 ? 0 : (layer == 1 ? 4194304 : 8388608)) + (size_t)r * n;
  const float* v = vin + layer * 2048;
  float part = 0.f;
  for (int c = lane * 8; c < n; c += 512) {
    short8 w8 = *(const short8*)(row + c);
    const float4* vp = (const float4*)(v + c);
    float4 a = vp[0], b = vp[1];
    float vs[8] = {a.x, a.y, a.z, a.w, b.x, b.y, b.z, b.w};
#pragma unroll
    for (int e = 0; e < 8; ++e) part += bf2f((uint16_t)((short*)&w8)[e]) * vs[e];
  }
  for (int o = 32; o; o >>= 1) part += __shfl_xor(part, o, 64);
  if (lane == 0) vout[layer * 2048 + r] = part;
}

// ---------------------------------------------------------------------------
// dual GEMM, fp8-e4m3: R3's 2-barrier schedule, BK=128 elems.
// LDS: 4 mats x [128][128B] = 64KB. 128 MFMA per 2 barriers.
// fp8 layout f(row,k) = k ^ ((row&7)<<4) ^ (((row>>3)&1)<<3):
// quarter-wave b64 reads cover all 32 banks exactly once (zero conflicts).
// accs scaling: B2 = 256*sigma^2; sd = sqrt(accs)*sdinv.
// ---------------------------------------------------------------------------
__global__ __launch_bounds__(256, 2) void gemm_dual_kernel(
    const uint8_t* __restrict__ Ab, const uint8_t* __restrict__ A2b,
    const uint8_t* __restrict__ Bb, const uint8_t* __restrict__ B2b,
    const float* __restrict__ eps, const float* __restrict__ bias,
    uint8_t* __restrict__ Oh, uint8_t* __restrict__ Oh2,
    float* __restrict__ Oy, int K, int N, int last, float sdinv, int nwgx) {
  __shared__ uint8_t lds[65536];  // A | A2 | B | B2, each [128][128B]
  const int t = threadIdx.x;
  const int w = t >> 6, lane = t & 63;

  // T1: bijective XCD swizzle (grid always % 8 == 0 here)
  const int nwg = gridDim.x;
  const int cpx = nwg >> 3;
  const int bid = blockIdx.x;
  const int logical = (bid & 7) * cpx + (bid >> 3);
  const int bx = logical % nwgx, by = logical / nwgx;

  const int m0 = by * 128, n0 = bx * 128;
  const int wm = (w >> 1) * 64, wn = (w & 1) * 64;
  const size_t Kb = (size_t)K;  // bytes per row

  f32x4 zero = {0.f, 0.f, 0.f, 0.f};
  f32x4 accm[4][4], accs[4][4];
#pragma unroll
  for (int i = 0; i < 4; ++i)
#pragma unroll
    for (int j = 0; j < 4; ++j) { accm[i][j] = zero; accs[i][j] = zero; }

  // staging: wave w stages matrix w (A, A2, B, B2), 16KB per K-tile
  const uint8_t* mats[4] = {Ab, A2b, Bb, B2b};
  const int rb = (w < 2) ? m0 : n0;
  const char* gsrc = (const char*)mats[w] + (size_t)rb * Kb;
  const int lrow = lane >> 3;          // 8 rows per iteration
  const int lcol = (lane & 7) * 16;    // 128B per row
  uint8_t* ltile = lds + w * 16384;

  int rowA[4], rowB[4];
#pragma unroll
  for (int i = 0; i < 4; ++i) {
    rowA[i] = wm + i * 16 + (lane & 15);
    rowB[i] = wn + i * 16 + (lane & 15);
  }
  const int klo = (lane >> 4) << 3;  // 8-byte sub-chunk within K=32 step

  const char* ldsc = (const char*)lds;
  const int nkt = K >> 7;
  for (int kt = 0; kt < nkt; ++kt) {
    const char* gb = gsrc + (size_t)kt * 128;
#pragma unroll
    for (int r = 0; r < 16; ++r) {
      gload16(gb + (size_t)(r * 8 + lrow) * Kb + lcol, ltile + r * 1024 + lane * 16);
    }
    __syncthreads();
#pragma unroll
    for (int kk = 0; kk < 4; ++kk) {
      const int ko = kk * 32 + klo;
      i64 af[4], a2f[4], bfr[4], b2f[4];
#pragma unroll
      for (int i = 0; i < 4; ++i) {
        int oa = rowA[i] * 128 +
                 ((ko ^ ((rowA[i] & 7) << 4)) ^ (((rowA[i] >> 3) & 1) << 3));
        int ob = rowB[i] * 128 +
                 ((ko ^ ((rowB[i] & 7) << 4)) ^ (((rowB[i] >> 3) & 1) << 3));
        af[i]  = *(const i64*)(ldsc + oa);
        a2f[i] = *(const i64*)(ldsc + 16384 + oa);
        bfr[i] = *(const i64*)(ldsc + 32768 + ob);
        b2f[i] = *(const i64*)(ldsc + 49152 + ob);
      }
#pragma unroll
      for (int i = 0; i < 4; ++i)
#pragma unroll
        for (int j = 0; j < 4; ++j) {
          accm[i][j] = __builtin_amdgcn_mfma_f32_16x16x32_fp8_fp8(af[i], bfr[j], accm[i][j], 0, 0, 0);
          accs[i][j] = __builtin_amdgcn_mfma_f32_16x16x32_fp8_fp8(a2f[i], b2f[j], accs[i][j], 0, 0, 0);
        }
    }
    __syncthreads();
  }
  // epilogue
#pragma unroll
  for (int j = 0; j < 4; ++j) {
    int n = n0 + wn + j * 16 + (lane & 15);
    float bn = bias[n];
#pragma unroll
    for (int i = 0; i < 4; ++i) {
      int mb = m0 + wm + i * 16 + ((lane >> 4) << 2);
      f32x4 am = accm[i][j], as = accs[i][j];
#pragma unroll
      for (int r = 0; r < 4; ++r) {
        int m = mb + r;
        float sd = sqrtf(fmaxf(as[r], 0.f)) * sdinv;
        float val = am[r] + sd * eps[(size_t)m * N + n] + bn;
        if (last) {
          Oy[(size_t)m * N + n] = val;
        } else {
          float h = fmaxf(val, 0.f);
          size_t ob = (size_t)m * N +
                      (size_t)((n ^ ((m & 7) << 4)) ^ (((m >> 3) & 1) << 3));
          Oh[ob] = f2fp8(h);
          Oh2[ob] = f2fp8(h * h * 0.0625f);
        }
      }
    }
  }
}

// ---------------------------------------------------------------------------
// finalize: reduce sim partials; tkld, tlip.
// sigma = sqrt(dot(v10,Bv10)/dot(v10,v10))
// ---------------------------------------------------------------------------
__device__ __forceinline__ float block_red(float v, int is_max, float* red) {
  int t = threadIdx.x;
  red[t] = v;
  __syncthreads();
  for (int o = 128; o >= 1; o >>= 1) {
    if (t < o) red[t] = is_max ? fmaxf(red[t], red[t + o]) : (red[t] + red[t + o]);
    __syncthreads();
  }
  float r = red[0];
  __syncthreads();
  return r;
}

__global__ __launch_bounds__(256) void finalize_kernel(const float* __restrict__ acc,
                                                       const float* __restrict__ v10,
                                                       const float* __restrict__ wv,
                                                       const float* __restrict__ partial,
                                                       float* __restrict__ out2) {
  __shared__ float red[256];
  __shared__ float smax[30];
  int t = threadIdx.x;
  int w = t >> 6, lane = t & 63;
  for (int sl = w; sl < 30; sl += 4) {
    float m = 0.f;
    for (int b = lane; b < 2048; b += 64) m = fmaxf(m, partial[sl * 2048 + b]);
    for (int o = 32; o; o >>= 1) m = fmaxf(m, __shfl_xor(m, o, 64));
    if (lane == 0) smax[sl] = m;
  }
  __syncthreads();
  float tlip = 0.f;
  for (int layer = 0; layer < 3; ++layer) {
    int ni = layer == 0 ? 1024 : 2048;
    int no = layer == 2 ? 1024 : 2048;
    float mr = 0.f, mc = 0.f, s2n = 0.f, s2d = 0.f;
    for (int i = t; i < ni; i += 256) mr = fmaxf(mr, acc[64 + layer * 2048 + i]);
    for (int j = t; j < no; j += 256) mc = fmaxf(mc, acc[6208 + layer * 2048 + j]);
    for (int j = t; j < no; j += 256) {
      float v = v10[layer * 2048 + j], wv_ = wv[layer * 2048 + j];
      s2n += v * wv_;
      s2d += v * v;
    }
    mr = block_red(mr, 1, red);
    mc = block_red(mc, 1, red);
    s2n = block_red(s2n, 0, red);
    s2d = block_red(s2d, 0, red);
    if (t == 0) {
      float sm = 0.f;
      for (int s = 0; s < 10; ++s) sm += smax[layer * 10 + s];
      sm *= 0.1f;
      float sigma = sqrtf(s2n / s2d);
      float res = sqrtf(mr) + sqrtf(mc);
      float l = res + sm + sigma;
      tlip += l * l;
    }
  }
  if (t == 0) {
    out2[0] = acc[0];
    out2[1] = tlip;
  }
}

// ---------------------------------------------------------------------------
extern "C" void kernel_launch(void* const* d_in, const int* in_sizes, int n_in,
                              void* d_out, int out_size, void* d_ws, size_t ws_size,
                              hipStream_t stream) {
  (void)in_sizes; (void)n_in; (void)out_size; (void)ws_size;
  const float* x = (const float*)d_in[0];
  const float* Wmu[3] = {(const float*)d_in[1], (const float*)d_in[9],  (const float*)d_in[17]};
  const float* Wp[3]  = {(const float*)d_in[2], (const float*)d_in[10], (const float*)d_in[18]};
  const float* bmu[3] = {(const float*)d_in[3], (const float*)d_in[11], (const float*)d_in[19]};
  const float* bp[3]  = {(const float*)d_in[4], (const float*)d_in[12], (const float*)d_in[20]};
  const float* epsw[3]= {(const float*)d_in[5], (const float*)d_in[13], (const float*)d_in[21]};
  const float* epsb[3]= {(const float*)d_in[6], (const float*)d_in[14], (const float*)d_in[22]};
  const float* u0[3]  = {(const float*)d_in[7], (const float*)d_in[15], (const float*)d_in[23]};
  const float* sim[3] = {(const float*)d_in[8], (const float*)d_in[16], (const float*)d_in[24]};

  char* ws = (char*)d_ws;
  uint8_t*  A0f  = (uint8_t*)(ws);                 // 8 MB  (x fp8)
  uint8_t*  A0f2 = (uint8_t*)(ws + 8388608);       // 8 MB  (x^2 fp8)
  uint8_t*  A1f  = (uint8_t*)(ws + 16777216);      // 16 MB (h1)
  uint8_t*  A1f2 = (uint8_t*)(ws + 33554432);      // 16 MB (h1^2/16)
  uint8_t*  A2f  = (uint8_t*)(ws + 50331648);      // 16 MB (h2)
  uint8_t*  A2f2 = (uint8_t*)(ws + 67108864);      // 16 MB (h2^2/16)
  uint8_t*  Wf   = (uint8_t*)(ws + 83886080);      // 8 MB  (W fp8)
  uint8_t*  Sf2  = (uint8_t*)(ws + 92274688);      // 8 MB  (256*sigma^2 fp8)
  uint16_t* Bmat = (uint16_t*)(ws + 100663296);    // ~19 MB bf16
  uint16_t* Sgbf = (uint16_t*)(ws + 119537664);    // 16 MB bf16 sigma
  uint16_t* Wt   = (uint16_t*)(ws + 136314880);    // 16 MB bf16 W^T
  float* bias    = (float*)(ws + 153092096);
  float* pbuf0   = (float*)(ws + 153116672);
  float* pbuf1   = (float*)(ws + 153141248);
  float* acc     = (float*)(ws + 153165824);       // [0] kld | [64..] row2 | [6208..] col2
  float* partial = (float*)(ws + 153215232);       // 30*2048 floats

  hipMemsetAsync(ws + 153165824, 0, 49408, stream);

  prep_w_kernel<<<dim3(32, 32, 3), 256, 0, stream>>>(
      Wmu[0], Wp[0], Wmu[1], Wp[1], Wmu[2], Wp[2], Wt, Wf, Sf2, Sgbf,
      acc + 64, acc + 6208, acc);
  prep_x_kernel<<<4096, 256, 0, stream>>>(x, A0f, A0f2);
  prep_bias_kernel<<<20, 256, 0, stream>>>(
      bmu[0], bp[0], epsb[0], bmu[1], bp[1], epsb[1], bmu[2], bp[2], epsb[2], bias, acc);
  sim_max_kernel<<<2048, 256, 0, stream>>>(sim[0], sim[1], sim[2], Sgbf, partial);

  // B = W^T W per layer (symmetric, bf16 out), one launch
  gemm_nt_kernel<<<dim3(16, 16, 3), 256, 0, stream>>>(Wt, Bmat);

  // v1 = W^T u0 ; then v_{k+1} = B v_k ; v10 in pbuf1, w = B v10 in pbuf0
  v1_kernel<<<1280, 256, 0, stream>>>(Wt, u0[0], u0[1], u0[2], pbuf0);
  for (int it = 0; it < 10; ++it) {
    const float* vin = (it & 1) ? pbuf1 : pbuf0;
    float* vout = (it & 1) ? pbuf0 : pbuf1;
    bmv_kernel<<<1280, 256, 0, stream>>>(Bmat, vin, vout);
  }

  float* y = (float*)d_out;
  gemm_dual_kernel<<<1024, 256, 0, stream>>>(
      A0f, A0f2, Wf, Sf2, epsw[0], bias, A1f, A1f2, nullptr,
      1024, 2048, 0, 0.0625f, 16);
  gemm_dual_kernel<<<1024, 256, 0, stream>>>(
      A1f, A1f2, Wf + 2097152, Sf2 + 2097152, epsw[1], bias + 2048, A2f, A2f2, nullptr,
      2048, 2048, 0, 0.25f, 16);
  gemm_dual_kernel<<<512, 256, 0, stream>>>(
      A2f, A2f2, Wf + 6291456, Sf2 + 6291456, epsw[2], bias + 4096, nullptr, nullptr, y,
      2048, 1024, 1, 0.25f, 8);

  finalize_kernel<<<1, 256, 0, stream>>>(acc, pbuf1, pbuf0, partial, y + 8388608);
}

// Round 14
// 726.718 us; speedup vs baseline: 1.3110x; 1.0017x over previous
//
#include <hip/hip_runtime.h>
#include <stdint.h>

typedef __attribute__((ext_vector_type(8))) __bf16 bf16x8;
typedef __attribute__((ext_vector_type(8))) short short8;
typedef __attribute__((ext_vector_type(4))) float f32x4;
typedef long long i64;

#define LOG_P01 (-2.302585093f)   // log(0.1)

__device__ __forceinline__ uint16_t f2bf(float f) {
  union { float f; uint32_t u; } v; v.f = f;
  uint32_t r = (v.u + 0x7fffu + ((v.u >> 16) & 1u)) >> 16;
  return (uint16_t)r;
}
__device__ __forceinline__ float bf2f(uint16_t u) {
  union { uint32_t u; float f; } v; v.u = ((uint32_t)u) << 16;
  return v.f;
}
__device__ __forceinline__ uint8_t f2fp8(float f) {
  return (uint8_t)(__builtin_amdgcn_cvt_pk_fp8_f32(f, f, 0, false) & 0xff);
}
__device__ __forceinline__ float softplus1(float x) { return 1e-6f + log1pf(expf(x)); }

__device__ __forceinline__ void gload16(const void* g, void* l) {
  __builtin_amdgcn_global_load_lds(
      (__attribute__((address_space(1))) void*)(g),
      (__attribute__((address_space(3))) void*)(l), 16, 0, 0);
}

// fp8 layout function (BK=64 rows): byte = k ^ (((row>>1)&7)<<3)
// involution per row; quarter-wave b64 reads cover all 32 banks exactly once.

// ---------------------------------------------------------------------------
// prep_w: sigma = 1e-6+softplus(W_p);
//  - Wt bf16 transposed swizzled (for gemm_nt, v1)
//  - Wf fp8 + Sf2 fp8 (= sigma^2 * 256) transposed, fp8-layout
//  - Sg bf16 plain (sim_max); row/col norm^2 partials; KLD partial
// ---------------------------------------------------------------------------
__global__ __launch_bounds__(256) void prep_w_kernel(
    const float* __restrict__ Wmu0, const float* __restrict__ Wp0,
    const float* __restrict__ Wmu1, const float* __restrict__ Wp1,
    const float* __restrict__ Wmu2, const float* __restrict__ Wp2,
    uint16_t* __restrict__ Wt, uint8_t* __restrict__ Wf, uint8_t* __restrict__ Sf2,
    uint16_t* __restrict__ Sg,
    float* __restrict__ row2, float* __restrict__ col2, float* __restrict__ kld) {
  const int layer = blockIdx.z;
  const int ni = (layer == 0) ? 1024 : 2048;
  const int no = (layer == 2) ? 1024 : 2048;
  if ((int)blockIdx.x >= (ni >> 6) || (int)blockIdx.y >= (no >> 6)) return;
  const float* Wmu = layer == 0 ? Wmu0 : (layer == 1 ? Wmu1 : Wmu2);
  const float* Wp  = layer == 0 ? Wp0  : (layer == 1 ? Wp1  : Wp2);
  const size_t wofs = layer == 0 ? 0 : (layer == 1 ? 2097152 : 6291456);
  uint16_t* wt = Wt + wofs;
  uint8_t* wf = Wf + wofs;
  uint8_t* sf = Sf2 + wofs;
  uint16_t* sgb = Sg + wofs;
  float* r2 = row2 + layer * 2048;
  float* c2 = col2 + layer * 2048;

  __shared__ uint16_t lmu[64][72];
  __shared__ __align__(16) uint8_t l8mu[64][80];
  __shared__ __align__(16) uint8_t l8s2[64][80];
  __shared__ float red[256];

  const int t = threadIdx.x;
  const int i0 = blockIdx.x * 64, j0 = blockIdx.y * 64;
  const int w = t >> 6, lane = t & 63;
  float colpart = 0.f, kpart = 0.f;
#pragma unroll
  for (int rep = 0; rep < 16; ++rep) {
    int il = rep * 4 + w;
    int jl = lane;
    size_t gi = (size_t)(i0 + il) * no + (j0 + jl);
    float mu = Wmu[gi], p = Wp[gi];
    float sg = softplus1(p);
    float s2 = sg * sg;
    kpart += 2.f * (LOG_P01 - logf(sg)) - 1.f + 100.f * s2 + 100.f * mu * mu;
    float rs = s2;
    for (int o = 32; o; o >>= 1) rs += __shfl_xor(rs, o, 64);
    if (lane == 0) atomicAdd(&r2[i0 + il], rs);
    colpart += s2;
    sgb[gi] = f2bf(sg);
    lmu[jl][il] = f2bf(mu);
    l8mu[jl][il] = f2fp8(mu);
    l8s2[jl][il] = f2fp8(s2 * 256.f);
  }
  red[t] = colpart;
  __syncthreads();
  if (t < 64) {
    float cs = red[t] + red[64 + t] + red[128 + t] + red[192 + t];
    atomicAdd(&c2[j0 + t], cs);
  }
  // bf16 Wt write-out (16B = 8 elems per chunk)
  const int Kb = ni * 2;
#pragma unroll
  for (int cc = 0; cc < 2; ++cc) {
    int c = cc * 256 + t;
    int nl = c >> 3, kc = c & 7;
    short8 vmu = *(const short8*)((const char*)&lmu[0][0] + nl * 144 + kc * 16);
    size_t db = (size_t)(j0 + nl) * Kb + (((i0 * 2 + kc * 16)) ^ ((nl & 7) << 4));
    *(short8*)((char*)wt + db) = vmu;
  }
  // fp8 write-out: position of logical k = k ^ g(j), g(j)=((j>>1)&7)<<3.
  // 16B chunk: relocate by g&48; swap 8B halves when g&8.
  {
    int nl = t >> 2, kc = t & 3;
    uint4 vm = *(const uint4*)&l8mu[nl][kc * 16];
    uint4 vs = *(const uint4*)&l8s2[nl][kc * 16];
    int g = ((nl >> 1) & 7) << 3;
    if (g & 8) {
      vm = make_uint4(vm.z, vm.w, vm.x, vm.y);
      vs = make_uint4(vs.z, vs.w, vs.x, vs.y);
    }
    size_t db = (size_t)(j0 + nl) * ni + (size_t)((i0 + kc * 16) ^ (g & 48));
    *(uint4*)(wf + db) = vm;
    *(uint4*)(sf + db) = vs;
  }
  __syncthreads();
  red[t] = kpart;
  __syncthreads();
  for (int o = 128; o >= 1; o >>= 1) {
    if (t < o) red[t] += red[t + o];
    __syncthreads();
  }
  if (t == 0) atomicAdd(kld, 0.5f * red[0]);
}

// ---------------------------------------------------------------------------
// prep_x: fp8(x), fp8(x*x) into fp8-layout [8192][1024B]
// ---------------------------------------------------------------------------
__global__ __launch_bounds__(256) void prep_x_kernel(const float* __restrict__ x,
                                                     uint8_t* __restrict__ Af,
                                                     uint8_t* __restrict__ Af2) {
  size_t c = (size_t)blockIdx.x * 256 + threadIdx.x;  // 8-elem chunk
  size_t gidx = c * 8;
  if (gidx >= (size_t)8192 * 1024) return;
  int m = (int)(gidx >> 10);
  int k0 = (int)(gidx & 1023);
  const float4* xp = (const float4*)(x + gidx);
  float4 a = xp[0], b = xp[1];
  int lo = __builtin_amdgcn_cvt_pk_fp8_f32(a.x, a.y, 0, false);
  lo = __builtin_amdgcn_cvt_pk_fp8_f32(a.z, a.w, lo, true);
  int hi = __builtin_amdgcn_cvt_pk_fp8_f32(b.x, b.y, 0, false);
  hi = __builtin_amdgcn_cvt_pk_fp8_f32(b.z, b.w, hi, true);
  int slo = __builtin_amdgcn_cvt_pk_fp8_f32(a.x * a.x, a.y * a.y, 0, false);
  slo = __builtin_amdgcn_cvt_pk_fp8_f32(a.z * a.z, a.w * a.w, slo, true);
  int shi = __builtin_amdgcn_cvt_pk_fp8_f32(b.x * b.x, b.y * b.y, 0, false);
  shi = __builtin_amdgcn_cvt_pk_fp8_f32(b.z * b.z, b.w * b.w, shi, true);
  int g = ((m >> 1) & 7) << 3;
  size_t ob = (size_t)m * 1024 + (size_t)(k0 ^ g);
  *(uint32_t*)(Af + ob) = (uint32_t)lo;
  *(uint32_t*)(Af + (ob ^ 4ull) + (((k0 ^ g) & 4) ? -4 : 4)) = 0;  // placeholder removed below
  (void)0;
  // 8B chunk stays contiguous under XOR of bits>=3:
  *(uint2*)(Af + ob) = make_uint2((uint32_t)lo, (uint32_t)hi);
  *(uint2*)(Af2 + ob) = make_uint2((uint32_t)slo, (uint32_t)shi);
}

// ---------------------------------------------------------------------------
// prep_bias: bias[n] = b_mu + softplus(b_p)*eps_b ; bias KLD
// ---------------------------------------------------------------------------
__global__ __launch_bounds__(256) void prep_bias_kernel(
    const float* bmu0, const float* bp0, const float* eb0,
    const float* bmu1, const float* bp1, const float* eb1,
    const float* bmu2, const float* bp2, const float* eb2,
    float* __restrict__ bias, float* __restrict__ kld) {
  int t = blockIdx.x * 256 + threadIdx.x;
  float kpart = 0.f;
  if (t < 5120) {
    int layer = t < 2048 ? 0 : (t < 4096 ? 1 : 2);
    int n = t - (layer == 0 ? 0 : (layer == 1 ? 2048 : 4096));
    const float* bmu = layer == 0 ? bmu0 : (layer == 1 ? bmu1 : bmu2);
    const float* bp  = layer == 0 ? bp0  : (layer == 1 ? bp1  : bp2);
    const float* eb  = layer == 0 ? eb0  : (layer == 1 ? eb1  : eb2);
    float mu = bmu[n], p = bp[n], e = eb[n];
    float sg = softplus1(p);
    bias[layer * 2048 + n] = mu + sg * e;
    kpart = 0.5f * (2.f * (LOG_P01 - logf(sg)) - 1.f + 100.f * sg * sg + 100.f * mu * mu);
  }
  for (int o = 32; o; o >>= 1) kpart += __shfl_xor(kpart, o, 64);
  if ((threadIdx.x & 63) == 0) atomicAdd(kld, kpart);
}

// ---------------------------------------------------------------------------
// sim_max: single linear grid-stride pass over concatenated sim (320MB).
// ---------------------------------------------------------------------------
__global__ __launch_bounds__(256) void sim_max_kernel(
    const float* __restrict__ s0, const float* __restrict__ s1,
    const float* __restrict__ s2, const uint16_t* __restrict__ Sg,
    float* __restrict__ partial) {
  __shared__ int lmax[30];
  if (threadIdx.x < 30) lmax[threadIdx.x] = 0;
  __syncthreads();
  const size_t stride = (size_t)gridDim.x * 256;
  for (size_t c = (size_t)blockIdx.x * 256 + threadIdx.x; c < 20971520; c += stride) {
    const float* sp; size_t within; const uint16_t* sgp; int slot_base, shift;
    if (c < 5242880)       { sp = s0; within = c;            sgp = Sg;           slot_base = 0;  shift = 19; }
    else if (c < 15728640) { sp = s1; within = c - 5242880;  sgp = Sg + 2097152; slot_base = 10; shift = 20; }
    else                   { sp = s2; within = c - 15728640; sgp = Sg + 6291456; slot_base = 20; shift = 19; }
    int s = (int)(within >> shift);
    size_t idx = within - ((size_t)s << shift);
    float4 v = ((const float4*)sp)[within];
    ushort4 sv = *(const ushort4*)(sgp + idx * 4);
    float m = fmaxf(fmaxf(v.x * bf2f(sv.x), v.y * bf2f(sv.y)),
                    fmaxf(v.z * bf2f(sv.z), v.w * bf2f(sv.w)));
    for (int o = 32; o; o >>= 1) m = fmaxf(m, __shfl_xor(m, o, 64));
    if ((threadIdx.x & 63) == 0)
      atomicMax(&lmax[slot_base + s], __float_as_int(fmaxf(m, 0.f)));
  }
  __syncthreads();
  if (threadIdx.x < 30)
    partial[threadIdx.x * 2048 + blockIdx.x] = __int_as_float(lmax[threadIdx.x]);
}

// ---------------------------------------------------------------------------
// gemm_nt (3 layers, SYMMETRIC): C = R @ R^T, bf16 out (feeds bmv only).
// ---------------------------------------------------------------------------
__global__ __launch_bounds__(256, 2) void gemm_nt_kernel(
    const uint16_t* __restrict__ Wt, uint16_t* __restrict__ Bmat) {
  const int layer = blockIdx.z;
  const int K = (layer == 0) ? 1024 : 2048;
  const int N = (layer == 2) ? 1024 : 2048;
  if ((int)blockIdx.x >= (N >> 7) || (int)blockIdx.y >= (N >> 7)) return;
  if (blockIdx.y < blockIdx.x) return;  // symmetric: keep by >= bx
  const uint16_t* R = Wt + (layer == 0 ? 0 : (layer == 1 ? 2097152 : 6291456));
  uint16_t* C = Bmat + (layer == 0 ? 0 : (layer == 1 ? 4194304 : 8388608));

  __shared__ uint16_t lds[16384];  // 32KB
  const int t = threadIdx.x;
  const int w = t >> 6, lane = t & 63;
  const int m0 = blockIdx.y * 128, n0 = blockIdx.x * 128;
  const int wm = (w >> 1) * 64, wn = (w & 1) * 64;
  const size_t Kb = (size_t)K * 2;

  f32x4 zero = {0.f, 0.f, 0.f, 0.f};
  f32x4 acc[4][4];
#pragma unroll
  for (int i = 0; i < 4; ++i)
#pragma unroll
    for (int j = 0; j < 4; ++j) acc[i][j] = zero;

  const int rb = ((w < 2) ? m0 : n0) + (w & 1) * 64;
  const char* gsrc = (const char*)R + (size_t)rb * Kb;
  uint16_t* ltile = lds + (w < 2 ? 0 : 8192) + (w & 1) * 4096;
  const int lrow = lane >> 3;
  const int lcol = (lane & 7) * 16;

  int offA[4][2], offB[4][2];
#pragma unroll
  for (int i = 0; i < 4; ++i) {
    int rowa = wm + i * 16 + (lane & 15);
    int rowb = wn + i * 16 + (lane & 15);
    int kp = (lane >> 4) << 4;
#pragma unroll
    for (int kk = 0; kk < 2; ++kk) {
      offA[i][kk] = (rowa << 7) + (((kk << 6) + kp) ^ ((rowa & 7) << 4));
      offB[i][kk] = (rowb << 7) + (((kk << 6) + kp) ^ ((rowb & 7) << 4));
    }
  }
  const char* ldsc = (const char*)lds;
  const int nkt = K >> 6;
  for (int kt = 0; kt < nkt; ++kt) {
    const char* gb = gsrc + (size_t)kt * 128;
#pragma unroll
    for (int r = 0; r < 8; ++r) {
      gload16(gb + (size_t)(r * 8 + lrow) * Kb + lcol, ltile + r * 512);
    }
    __syncthreads();
#pragma unroll
    for (int kk = 0; kk < 2; ++kk) {
      bf16x8 af[4], bfr[4];
#pragma unroll
      for (int i = 0; i < 4; ++i) {
        af[i]  = *(const bf16x8*)(ldsc + offA[i][kk]);
        bfr[i] = *(const bf16x8*)(ldsc + 16384 + offB[i][kk]);
      }
#pragma unroll
      for (int i = 0; i < 4; ++i)
#pragma unroll
        for (int j = 0; j < 4; ++j)
          acc[i][j] = __builtin_amdgcn_mfma_f32_16x16x32_bf16(af[i], bfr[j], acc[i][j], 0, 0, 0);
    }
    __syncthreads();
  }
  const int mirror = (blockIdx.y > blockIdx.x);
#pragma unroll
  for (int j = 0; j < 4; ++j) {
    int n = n0 + wn + j * 16 + (lane & 15);
#pragma unroll
    for (int i = 0; i < 4; ++i) {
      int mb = m0 + wm + i * 16 + ((lane >> 4) << 2);
      f32x4 a = acc[i][j];
#pragma unroll
      for (int r = 0; r < 4; ++r) {
        uint16_t hb = f2bf(a[r]);
        C[(size_t)(mb + r) * N + n] = hb;
        if (mirror) C[(size_t)n * N + (mb + r)] = hb;
      }
    }
  }
}

// ---------------------------------------------------------------------------
// v1: v = W^T u0 per layer — wave per row of Wt (bf16 swizzled), fp32 accum
// ---------------------------------------------------------------------------
__global__ __launch_bounds__(256) void v1_kernel(const uint16_t* __restrict__ Wt,
                                                 const float* u00, const float* u01,
                                                 const float* u02,
                                                 float* __restrict__ vout) {
  int gw = (blockIdx.x * 256 + threadIdx.x) >> 6;  // 0..5119
  int lane = threadIdx.x & 63;
  int layer = gw < 2048 ? 0 : (gw < 4096 ? 1 : 2);
  int j = gw - (layer == 0 ? 0 : (layer == 1 ? 2048 : 4096));
  int ni = layer == 0 ? 1024 : 2048;
  const uint16_t* row = Wt + (layer == 0 ? 0 : (layer == 1 ? 2097152 : 6291456)) + (size_t)j * ni;
  const float* u0 = layer == 0 ? u00 : (layer == 1 ? u01 : u02);
  int nc = ni >> 3;
  float part = 0.f;
  for (int c = lane; c < nc; c += 64) {
    int bo = (c * 16) ^ ((j & 7) << 4);
    short8 v = *(const short8*)((const char*)row + bo);
    const float4* up = (const float4*)(u0 + c * 8);
    float4 a = up[0], b = up[1];
    float us[8] = {a.x, a.y, a.z, a.w, b.x, b.y, b.z, b.w};
#pragma unroll
    for (int e = 0; e < 8; ++e) part += bf2f((uint16_t)((short*)&v)[e]) * us[e];
  }
  for (int o = 32; o; o >>= 1) part += __shfl_xor(part, o, 64);
  if (lane == 0) vout[layer * 2048 + j] = part;
}

// ---------------------------------------------------------------------------
// bmv: vout = B vin for all 3 layers (wave per row, bf16 B, fp32 accum)
// ---------------------------------------------------------------------------
__global__ __launch_bounds__(256) void bmv_kernel(const uint16_t* __restrict__ Bm,
                                                  const float* __restrict__ vin,
                                                  float* __restrict__ vout) {
  int gw = (blockIdx.x * 256 + threadIdx.x) >> 6;  // 0..5119
  int lane = threadIdx.x & 63;
  int layer = gw < 2048 ? 0 : (gw < 4096 ? 1 : 2);
  int r = gw - (layer == 0 ? 0 : (layer == 1 ? 2048 : 4096));
  int n = layer == 2 ? 1024 : 2048;
  const uint16_t* row = Bm + (layer == 0 ? 0 : (layer == 1 ? 4194304 : 8388608)) + (size_t)r * n;
  const float* v = vin + layer * 2048;
  float part = 0.f;
  for (int c = lane * 8; c < n; c += 512) {
    short8 w8 = *(const short8*)(row + c);
    const float4* vp = (const float4*)(v + c);
    float4 a = vp[0], b = vp[1];
    float vs[8] = {a.x, a.y, a.z, a.w, b.x, b.y, b.z, b.w};
#pragma unroll
    for (int e = 0; e < 8; ++e) part += bf2f((uint16_t)((short*)&w8)[e]) * vs[e];
  }
  for (int o = 32; o; o >>= 1) part += __shfl_xor(part, o, 64);
  if (lane == 0) vout[layer * 2048 + r] = part;
}

// ---------------------------------------------------------------------------
// dual GEMM, fp8-e4m3 + T4 counted-vmcnt double-buffer. BK=64 elems.
// LDS: 2 stages x (A|A2|B|B2) x [128][64B] = 2 x 32768 B (stage stride 32768 —
// R8's fatal bug was 16384 here). Per K-tile: issue 8 gloads (kt+1 -> buf^1),
// vmcnt(8) [kt done, kt+1 in flight ACROSS barrier], s_barrier, 32 b64
// ds_reads + 64 MFMA, lgkmcnt(0), s_barrier. sched_barrier(0) fences (r#18).
// Layout f(r,k)=k^(((r>>1)&7)<<3): quarter-wave covers all 32 banks once.
// ---------------------------------------------------------------------------
__global__ __launch_bounds__(256, 2) void gemm_dual_kernel(
    const uint8_t* __restrict__ Ab, const uint8_t* __restrict__ A2b,
    const uint8_t* __restrict__ Bb, const uint8_t* __restrict__ B2b,
    const float* __restrict__ eps, const float* __restrict__ bias,
    uint8_t* __restrict__ Oh, uint8_t* __restrict__ Oh2,
    float* __restrict__ Oy, int K, int N, int last, float sdinv, int nwgx) {
  __shared__ uint8_t lds[65536];
  const int t = threadIdx.x;
  const int w = t >> 6, lane = t & 63;

  // T1: bijective XCD swizzle (grid always % 8 == 0 here)
  const int nwg = gridDim.x;
  const int cpx = nwg >> 3;
  const int bid = blockIdx.x;
  const int logical = (bid & 7) * cpx + (bid >> 3);
  const int bx = logical % nwgx, by = logical / nwgx;

  const int m0 = by * 128, n0 = bx * 128;
  const int wm = (w >> 1) * 64, wn = (w & 1) * 64;
  const size_t Kb = (size_t)K;  // bytes per row

  f32x4 zero = {0.f, 0.f, 0.f, 0.f};
  f32x4 accm[4][4], accs[4][4];
#pragma unroll
  for (int i = 0; i < 4; ++i)
#pragma unroll
    for (int j = 0; j < 4; ++j) { accm[i][j] = zero; accs[i][j] = zero; }

  // staging: wave w stages matrix w: [128][64B] = 8 gloads per tile
  const uint8_t* mats[4] = {Ab, A2b, Bb, B2b};
  const int rb = (w < 2) ? m0 : n0;
  const char* gsrc = (const char*)mats[w] + (size_t)rb * Kb;
  const int srow = lane >> 2;          // 16 rows per gload pass
  const int scol = (lane & 3) * 16;
  const int lwofs = w * 8192;          // mat base within stage

  int rowA[4], rowB[4];
#pragma unroll
  for (int i = 0; i < 4; ++i) {
    rowA[i] = wm + i * 16 + (lane & 15);
    rowB[i] = wn + i * 16 + (lane & 15);
  }
  const int klo = (lane >> 4) << 3;  // {0,8,16,24}

  const char* ldsc = (const char*)lds;
  const int nkt = K >> 6;

  // prologue: stage K-tile 0 into stage 0
  {
    char* lw = (char*)lds + lwofs;
#pragma unroll
    for (int r = 0; r < 8; ++r)
      gload16(gsrc + (size_t)(r * 16 + srow) * Kb + scol, lw + r * 1024 + lane * 16);
  }
  __builtin_amdgcn_sched_barrier(0);

  int cur = 0;
  for (int kt = 0; kt < nkt; ++kt) {
    if (kt + 1 < nkt) {
      char* lw = (char*)lds + (cur ^ 1) * 32768 + lwofs;
      const char* gb = gsrc + (size_t)(kt + 1) * 64;
#pragma unroll
      for (int r = 0; r < 8; ++r)
        gload16(gb + (size_t)(r * 16 + srow) * Kb + scol, lw + r * 1024 + lane * 16);
      __builtin_amdgcn_sched_barrier(0);
      asm volatile("s_waitcnt vmcnt(8)" ::: "memory");
    } else {
      __builtin_amdgcn_sched_barrier(0);
      asm volatile("s_waitcnt vmcnt(0)" ::: "memory");
    }
    __builtin_amdgcn_s_barrier();
    __builtin_amdgcn_sched_barrier(0);
    const char* sb = ldsc + cur * 32768;
#pragma unroll
    for (int kk = 0; kk < 2; ++kk) {
      const int ko = kk * 32 + klo;
      i64 af[4], a2f[4], bfr[4], b2f[4];
#pragma unroll
      for (int i = 0; i < 4; ++i) {
        int oa = rowA[i] * 64 + (ko ^ (((rowA[i] >> 1) & 7) << 3));
        int ob = rowB[i] * 64 + (ko ^ (((rowB[i] >> 1) & 7) << 3));
        af[i]  = *(const i64*)(sb + oa);
        a2f[i] = *(const i64*)(sb + 8192 + oa);
        bfr[i] = *(const i64*)(sb + 16384 + ob);
        b2f[i] = *(const i64*)(sb + 24576 + ob);
      }
#pragma unroll
      for (int i = 0; i < 4; ++i)
#pragma unroll
        for (int j = 0; j < 4; ++j) {
          accm[i][j] = __builtin_amdgcn_mfma_f32_16x16x32_fp8_fp8(af[i], bfr[j], accm[i][j], 0, 0, 0);
          accs[i][j] = __builtin_amdgcn_mfma_f32_16x16x32_fp8_fp8(a2f[i], b2f[j], accs[i][j], 0, 0, 0);
        }
    }
    asm volatile("s_waitcnt lgkmcnt(0)" ::: "memory");
    __builtin_amdgcn_sched_barrier(0);
    __builtin_amdgcn_s_barrier();
    cur ^= 1;
  }
  __syncthreads();

  // epilogue
#pragma unroll
  for (int j = 0; j < 4; ++j) {
    int n = n0 + wn + j * 16 + (lane & 15);
    float bn = bias[n];
#pragma unroll
    for (int i = 0; i < 4; ++i) {
      int mb = m0 + wm + i * 16 + ((lane >> 4) << 2);
      f32x4 am = accm[i][j], as = accs[i][j];
#pragma unroll
      for (int r = 0; r < 4; ++r) {
        int m = mb + r;
        float sd = sqrtf(fmaxf(as[r], 0.f)) * sdinv;
        float val = am[r] + sd * eps[(size_t)m * N + n] + bn;
        if (last) {
          Oy[(size_t)m * N + n] = val;
        } else {
          float h = fmaxf(val, 0.f);
          size_t ob = (size_t)m * N + (size_t)(n ^ (((m >> 1) & 7) << 3));
          Oh[ob] = f2fp8(h);
          Oh2[ob] = f2fp8(h * h * 0.0625f);
        }
      }
    }
  }
}

// ---------------------------------------------------------------------------
// finalize: reduce sim partials; tkld, tlip.
// sigma = sqrt(dot(v10,Bv10)/dot(v10,v10))
// ---------------------------------------------------------------------------
__device__ __forceinline__ float block_red(float v, int is_max, float* red) {
  int t = threadIdx.x;
  red[t] = v;
  __syncthreads();
  for (int o = 128; o >= 1; o >>= 1) {
    if (t < o) red[t] = is_max ? fmaxf(red[t], red[t + o]) : (red[t] + red[t + o]);
    __syncthreads();
  }
  float r = red[0];
  __syncthreads();
  return r;
}

__global__ __launch_bounds__(256) void finalize_kernel(const float* __restrict__ acc,
                                                       const float* __restrict__ v10,
                                                       const float* __restrict__ wv,
                                                       const float* __restrict__ partial,
                                                       float* __restrict__ out2) {
  __shared__ float red[256];
  __shared__ float smax[30];
  int t = threadIdx.x;
  int w = t >> 6, lane = t & 63;
  for (int sl = w; sl < 30; sl += 4) {
    float m = 0.f;
    for (int b = lane; b < 2048; b += 64) m = fmaxf(m, partial[sl * 2048 + b]);
    for (int o = 32; o; o >>= 1) m = fmaxf(m, __shfl_xor(m, o, 64));
    if (lane == 0) smax[sl] = m;
  }
  __syncthreads();
  float tlip = 0.f;
  for (int layer = 0; layer < 3; ++layer) {
    int ni = layer == 0 ? 1024 : 2048;
    int no = layer == 2 ? 1024 : 2048;
    float mr = 0.f, mc = 0.f, s2n = 0.f, s2d = 0.f;
    for (int i = t; i < ni; i += 256) mr = fmaxf(mr, acc[64 + layer * 2048 + i]);
    for (int j = t; j < no; j += 256) mc = fmaxf(mc, acc[6208 + layer * 2048 + j]);
    for (int j = t; j < no; j += 256) {
      float v = v10[layer * 2048 + j], wv_ = wv[layer * 2048 + j];
      s2n += v * wv_;
      s2d += v * v;
    }
    mr = block_red(mr, 1, red);
    mc = block_red(mc, 1, red);
    s2n = block_red(s2n, 0, red);
    s2d = block_red(s2d, 0, red);
    if (t == 0) {
      float sm = 0.f;
      for (int s = 0; s < 10; ++s) sm += smax[layer * 10 + s];
      sm *= 0.1f;
      float sigma = sqrtf(s2n / s2d);
      float res = sqrtf(mr) + sqrtf(mc);
      float l = res + sm + sigma;
      tlip += l * l;
    }
  }
  if (t == 0) {
    out2[0] = acc[0];
    out2[1] = tlip;
  }
}

// ---------------------------------------------------------------------------
extern "C" void kernel_launch(void* const* d_in, const int* in_sizes, int n_in,
                              void* d_out, int out_size, void* d_ws, size_t ws_size,
                              hipStream_t stream) {
  (void)in_sizes; (void)n_in; (void)out_size; (void)ws_size;
  const float* x = (const float*)d_in[0];
  const float* Wmu[3] = {(const float*)d_in[1], (const float*)d_in[9],  (const float*)d_in[17]};
  const float* Wp[3]  = {(const float*)d_in[2], (const float*)d_in[10], (const float*)d_in[18]};
  const float* bmu[3] = {(const float*)d_in[3], (const float*)d_in[11], (const float*)d_in[19]};
  const float* bp[3]  = {(const float*)d_in[4], (const float*)d_in[12], (const float*)d_in[20]};
  const float* epsw[3]= {(const float*)d_in[5], (const float*)d_in[13], (const float*)d_in[21]};
  const float* epsb[3]= {(const float*)d_in[6], (const float*)d_in[14], (const float*)d_in[22]};
  const float* u0[3]  = {(const float*)d_in[7], (const float*)d_in[15], (const float*)d_in[23]};
  const float* sim[3] = {(const float*)d_in[8], (const float*)d_in[16], (const float*)d_in[24]};

  char* ws = (char*)d_ws;
  uint8_t*  A0f  = (uint8_t*)(ws);                 // 8 MB  (x fp8)
  uint8_t*  A0f2 = (uint8_t*)(ws + 8388608);       // 8 MB  (x^2 fp8)
  uint8_t*  A1f  = (uint8_t*)(ws + 16777216);      // 16 MB (h1)
  uint8_t*  A1f2 = (uint8_t*)(ws + 33554432);      // 16 MB (h1^2/16)
  uint8_t*  A2f  = (uint8_t*)(ws + 50331648);      // 16 MB (h2)
  uint8_t*  A2f2 = (uint8_t*)(ws + 67108864);      // 16 MB (h2^2/16)
  uint8_t*  Wf   = (uint8_t*)(ws + 83886080);      // 8 MB  (W fp8)
  uint8_t*  Sf2  = (uint8_t*)(ws + 92274688);      // 8 MB  (256*sigma^2 fp8)
  uint16_t* Bmat = (uint16_t*)(ws + 100663296);    // ~19 MB bf16
  uint16_t* Sgbf = (uint16_t*)(ws + 119537664);    // 16 MB bf16 sigma
  uint16_t* Wt   = (uint16_t*)(ws + 136314880);    // 16 MB bf16 W^T
  float* bias    = (float*)(ws + 153092096);
  float* pbuf0   = (float*)(ws + 153116672);
  float* pbuf1   = (float*)(ws + 153141248);
  float* acc     = (float*)(ws + 153165824);       // [0] kld | [64..] row2 | [6208..] col2
  float* partial = (float*)(ws + 153215232);       // 30*2048 floats

  hipMemsetAsync(ws + 153165824, 0, 49408, stream);

  prep_w_kernel<<<dim3(32, 32, 3), 256, 0, stream>>>(
      Wmu[0], Wp[0], Wmu[1], Wp[1], Wmu[2], Wp[2], Wt, Wf, Sf2, Sgbf,
      acc + 64, acc + 6208, acc);
  prep_x_kernel<<<4096, 256, 0, stream>>>(x, A0f, A0f2);
  prep_bias_kernel<<<20, 256, 0, stream>>>(
      bmu[0], bp[0], epsb[0], bmu[1], bp[1], epsb[1], bmu[2], bp[2], epsb[2], bias, acc);
  sim_max_kernel<<<2048, 256, 0, stream>>>(sim[0], sim[1], sim[2], Sgbf, partial);

  // B = W^T W per layer (symmetric, bf16 out), one launch
  gemm_nt_kernel<<<dim3(16, 16, 3), 256, 0, stream>>>(Wt, Bmat);

  // v1 = W^T u0 ; then v_{k+1} = B v_k ; v10 in pbuf1, w = B v10 in pbuf0
  v1_kernel<<<1280, 256, 0, stream>>>(Wt, u0[0], u0[1], u0[2], pbuf0);
  for (int it = 0; it < 10; ++it) {
    const float* vin = (it & 1) ? pbuf1 : pbuf0;
    float* vout = (it & 1) ? pbuf0 : pbuf1;
    bmv_kernel<<<1280, 256, 0, stream>>>(Bmat, vin, vout);
  }

  float* y = (float*)d_out;
  gemm_dual_kernel<<<1024, 256, 0, stream>>>(
      A0f, A0f2, Wf, Sf2, epsw[0], bias, A1f, A1f2, nullptr,
      1024, 2048, 0, 0.0625f, 16);
  gemm_dual_kernel<<<1024, 256, 0, stream>>>(
      A1f, A1f2, Wf + 2097152, Sf2 + 2097152, epsw[1], bias + 2048, A2f, A2f2, nullptr,
      2048, 2048, 0, 0.25f, 16);
  gemm_dual_kernel<<<512, 256, 0, stream>>>(
      A2f, A2f2, Wf + 6291456, Sf2 + 6291456, epsw[2], bias + 4096, nullptr, nullptr, y,
      2048, 1024, 1, 0.25f, 8);

  finalize_kernel<<<1, 256, 0, stream>>>(acc, pbuf1, pbuf0, partial, y + 8388608);
}